// Round 1
// baseline (793.592 us; speedup 1.0000x reference)
//
#include <hip/hip_runtime.h>
#include <hip/hip_bf16.h>

// GCN2: 3x GCNConv(relu,relu,none) + global_mean_pool + linear head.
// N=50000 nodes, E=800000 edges, HIDDEN=128, F_IN=11, CLASSES=19, G=2048.
// Strategy: build CSR (by dst) once per launch, then aggregation is a
// wave-per-node gather (no atomics in hot loop). GEMMs are fp32 vector
// (no fp32 MFMA on CDNA4), LDS-staged A-rows, W streamed through L1/L2.

#define HIDDEN 128
#define F_IN 11
#define NCLS 19

// ---------------- CSR build ----------------

__global__ void count_kernel(const int* __restrict__ dst, int* __restrict__ cnt, int E) {
    int e = blockIdx.x * blockDim.x + threadIdx.x;
    if (e < E) atomicAdd(&cnt[dst[e]], 1);
}

// single-block chunked exclusive scan over n counts -> offs[0..n], cursor copy
__global__ void scan_kernel(const int* __restrict__ cnt, int* __restrict__ offs,
                            int* __restrict__ cursor, int n) {
    __shared__ int buf[1024];
    __shared__ int carry_s;
    int tid = threadIdx.x;
    if (tid == 0) carry_s = 0;
    __syncthreads();
    for (int base = 0; base < n; base += 1024) {
        int i = base + tid;
        int v = (i < n) ? cnt[i] : 0;
        buf[tid] = v;
        __syncthreads();
        for (int off = 1; off < 1024; off <<= 1) {
            int t = (tid >= off) ? buf[tid - off] : 0;
            __syncthreads();
            buf[tid] += t;
            __syncthreads();
        }
        int excl = buf[tid] - v;
        int carry = carry_s;
        if (i < n) { offs[i] = carry + excl; cursor[i] = carry + excl; }
        __syncthreads();
        if (tid == 0) carry_s = carry + buf[1023];
        __syncthreads();
    }
    if (tid == 0) offs[n] = carry_s;
}

__global__ void dinv_kernel(const int* __restrict__ cnt, float* __restrict__ dinv, int n) {
    int i = blockIdx.x * blockDim.x + threadIdx.x;
    if (i < n) dinv[i] = 1.0f / sqrtf((float)cnt[i] + 1.0f);
}

__global__ void fill_csr_kernel(const int* __restrict__ src, const int* __restrict__ dst,
                                const float* __restrict__ dinv, int* __restrict__ cursor,
                                int* __restrict__ csr_src, float* __restrict__ csr_norm, int E) {
    int e = blockIdx.x * blockDim.x + threadIdx.x;
    if (e >= E) return;
    int s = src[e], d = dst[e];
    int pos = atomicAdd(&cursor[d], 1);
    csr_src[pos] = s;
    csr_norm[pos] = dinv[s] * dinv[d];
}

// ---------------- GEMMs (fp32 vector) ----------------

// x[n,11] @ W[11,128] -> out[n,128]; block=256 handles 2 nodes
__global__ void gemm_in_kernel(const float* __restrict__ x, const float* __restrict__ W,
                               float* __restrict__ out, int n) {
    __shared__ float Ws[F_IN * HIDDEN];
    __shared__ float xs[2][F_IN];
    int tid = threadIdx.x;
    for (int i = tid; i < F_IN * HIDDEN; i += 256) Ws[i] = W[i];
    if (tid < 2 * F_IN) {
        int r = tid / F_IN, c = tid % F_IN;
        long nn = (long)blockIdx.x * 2 + r;
        xs[r][c] = (nn < n) ? x[nn * F_IN + c] : 0.f;
    }
    __syncthreads();
    long node = (long)blockIdx.x * 2 + (tid >> 7);
    int f = tid & 127;
    int local = tid >> 7;
    if (node < n) {
        float acc = 0.f;
#pragma unroll
        for (int k = 0; k < F_IN; ++k) acc += xs[local][k] * Ws[k * HIDDEN + f];
        out[node * HIDDEN + f] = acc;
    }
}

// A[n,128] @ W[128,128] -> out[n,128]; block=256 handles 8 nodes, 4 feats/thread
__global__ void gemm128_kernel(const float* __restrict__ A, const float* __restrict__ W,
                               float* __restrict__ out, int n) {
    __shared__ float As[8 * HIDDEN];
    int tid = threadIdx.x;
    long base = (long)blockIdx.x * 8;
    int rows = n - (int)base; if (rows > 8) rows = 8;
    int lrow = tid >> 5;
    if (lrow < rows)
        ((float4*)As)[tid] = ((const float4*)(A + (base + lrow) * HIDDEN))[tid & 31];
    __syncthreads();
    int node = tid >> 5;
    int fq = tid & 31;
    if (node < rows) {
        float4 acc = {0.f, 0.f, 0.f, 0.f};
        const float* Ar = As + node * HIDDEN;
#pragma unroll 8
        for (int k = 0; k < HIDDEN; ++k) {
            float a = Ar[k];
            float4 w = ((const float4*)(W + k * HIDDEN))[fq];
            acc.x += a * w.x; acc.y += a * w.y; acc.z += a * w.z; acc.w += a * w.w;
        }
        ((float4*)(out + (base + node) * HIDDEN))[fq] = acc;
    }
}

// ---------------- Aggregation (wave per node) ----------------

__global__ void agg_kernel(const float* __restrict__ h, const int* __restrict__ offs,
                           const int* __restrict__ csr_src, const float* __restrict__ csr_norm,
                           const float* __restrict__ dinv, const float* __restrict__ bias,
                           float* __restrict__ out, int n, int do_relu) {
    int node = (int)((blockIdx.x * (long)blockDim.x + threadIdx.x) >> 6);
    int lane = threadIdx.x & 63;
    if (node >= n) return;
    int beg = offs[node], end = offs[node + 1];
    float2 acc = {0.f, 0.f};
    for (int e = beg; e < end; ++e) {
        int s = csr_src[e];
        float w = csr_norm[e];
        float2 v = ((const float2*)(h + (long)s * HIDDEN))[lane];
        acc.x += w * v.x;
        acc.y += w * v.y;
    }
    float di = dinv[node];
    float sl = di * di;
    float2 hv = ((const float2*)(h + (long)node * HIDDEN))[lane];
    acc.x += sl * hv.x + bias[lane * 2];
    acc.y += sl * hv.y + bias[lane * 2 + 1];
    if (do_relu) { acc.x = fmaxf(acc.x, 0.f); acc.y = fmaxf(acc.y, 0.f); }
    ((float2*)(out + (long)node * HIDDEN))[lane] = acc;
}

// ---------------- Pool + head ----------------

__global__ void pool_kernel(const float* __restrict__ h, const int* __restrict__ batch,
                            float* __restrict__ pool, float* __restrict__ cnt, int n) {
    int node = (int)((blockIdx.x * (long)blockDim.x + threadIdx.x) >> 6);
    int lane = threadIdx.x & 63;
    if (node >= n) return;
    int g = batch[node];
    float2 v = ((const float2*)(h + (long)node * HIDDEN))[lane];
    atomicAdd(pool + (long)g * HIDDEN + lane * 2, v.x);
    atomicAdd(pool + (long)g * HIDDEN + lane * 2 + 1, v.y);
    if (lane == 0) atomicAdd(cnt + g, 1.0f);
}

__global__ void final_kernel(const float* __restrict__ pool, const float* __restrict__ cnt,
                             const float* __restrict__ Wl, const float* __restrict__ bl,
                             float* __restrict__ out, int G) {
    __shared__ float ps[HIDDEN];
    int g = blockIdx.x;
    int tid = threadIdx.x; // 64
    float inv = 1.0f / fmaxf(cnt[g], 1.0f);
    ps[tid] = pool[(long)g * HIDDEN + tid] * inv;
    ps[tid + 64] = pool[(long)g * HIDDEN + tid + 64] * inv;
    __syncthreads();
    if (tid < NCLS) {
        float acc = bl[tid];
#pragma unroll 8
        for (int k = 0; k < HIDDEN; ++k) acc += ps[k] * Wl[k * NCLS + tid];
        out[(long)g * NCLS + tid] = acc;
    }
}

// ---------------- launch ----------------

static inline size_t align256(size_t x) { return (x + 255) & ~(size_t)255; }

extern "C" void kernel_launch(void* const* d_in, const int* in_sizes, int n_in,
                              void* d_out, int out_size, void* d_ws, size_t ws_size,
                              hipStream_t stream) {
    const float* x    = (const float*)d_in[0];
    const int*   ei   = (const int*)d_in[1];
    const int*   batch= (const int*)d_in[2];
    const float* W1   = (const float*)d_in[3];
    const float* b1   = (const float*)d_in[4];
    const float* W2   = (const float*)d_in[5];
    const float* b2   = (const float*)d_in[6];
    const float* W3   = (const float*)d_in[7];
    const float* b3   = (const float*)d_in[8];
    const float* Wl   = (const float*)d_in[9];
    const float* bl   = (const float*)d_in[10];
    float* out = (float*)d_out;

    const int N = in_sizes[0] / F_IN;
    const int E = in_sizes[1] / 2;
    const int G = out_size / NCLS;
    const int* src = ei;
    const int* dst = ei + E;

    // workspace carve-up
    char* p = (char*)d_ws;
    size_t off = 0;
    int*   deg_cnt  = (int*)(p + off);  off = align256(off + (size_t)N * 4);
    int*   offs     = (int*)(p + off);  off = align256(off + (size_t)(N + 1) * 4);
    int*   cursor   = (int*)(p + off);  off = align256(off + (size_t)N * 4);
    float* dinv     = (float*)(p + off);off = align256(off + (size_t)N * 4);
    int*   csr_src  = (int*)(p + off);  off = align256(off + (size_t)E * 4);
    float* csr_norm = (float*)(p + off);off = align256(off + (size_t)E * 4);
    float* pool     = (float*)(p + off);off = align256(off + (size_t)G * (HIDDEN + 1) * 4);
    float* gcnt     = pool + (size_t)G * HIDDEN;
    float* h_a      = (float*)(p + off);off = align256(off + (size_t)N * HIDDEN * 4);
    float* h_b      = (float*)(p + off);off = align256(off + (size_t)N * HIDDEN * 4);
    (void)ws_size; (void)n_in;

    // zero the accumulated regions (ws is re-poisoned 0xAA before every call)
    hipMemsetAsync(deg_cnt, 0, (size_t)N * 4, stream);
    hipMemsetAsync(pool, 0, (size_t)G * (HIDDEN + 1) * 4, stream);

    // CSR build
    count_kernel<<<(E + 255) / 256, 256, 0, stream>>>(dst, deg_cnt, E);
    scan_kernel<<<1, 1024, 0, stream>>>(deg_cnt, offs, cursor, N);
    dinv_kernel<<<(N + 255) / 256, 256, 0, stream>>>(deg_cnt, dinv, N);
    fill_csr_kernel<<<(E + 255) / 256, 256, 0, stream>>>(src, dst, dinv, cursor,
                                                         csr_src, csr_norm, E);

    const int aggBlocks = (N + 3) / 4;  // 4 waves/block, wave per node

    // layer 1: x@W1 -> h_a ; agg -> h_b (relu)
    gemm_in_kernel<<<(N + 1) / 2, 256, 0, stream>>>(x, W1, h_a, N);
    agg_kernel<<<aggBlocks, 256, 0, stream>>>(h_a, offs, csr_src, csr_norm, dinv, b1, h_b, N, 1);

    // layer 2: h_b@W2 -> h_a ; agg -> h_b (relu)
    gemm128_kernel<<<(N + 7) / 8, 256, 0, stream>>>(h_b, W2, h_a, N);
    agg_kernel<<<aggBlocks, 256, 0, stream>>>(h_a, offs, csr_src, csr_norm, dinv, b2, h_b, N, 1);

    // layer 3: h_b@W3 -> h_a ; agg -> h_b (no relu)
    gemm128_kernel<<<(N + 7) / 8, 256, 0, stream>>>(h_b, W3, h_a, N);
    agg_kernel<<<aggBlocks, 256, 0, stream>>>(h_a, offs, csr_src, csr_norm, dinv, b3, h_b, N, 0);

    // mean pool + head
    pool_kernel<<<aggBlocks, 256, 0, stream>>>(h_b, batch, pool, gcnt, N);
    final_kernel<<<G, 64, 0, stream>>>(pool, gcnt, Wl, bl, out, G);
}

// Round 2
// 633.886 us; speedup vs baseline: 1.2519x; 1.2519x over previous
//
#include <hip/hip_runtime.h>
#include <hip/hip_bf16.h>

// GCN2: 3x GCNConv(relu,relu,none) + global_mean_pool + linear head.
// N=50000 nodes, E=800000 edges, HIDDEN=128, F_IN=11, CLASSES=19, G=2048.
// R1: gemm128 rewritten as LDS-tiled register-blocked GEMM (was latency-bound
// at 13.6% VALUBusy streaming W from L2); scan rewritten shuffle-based.

#define HIDDEN 128
#define F_IN 11
#define NCLS 19

// ---------------- CSR build ----------------

__global__ void count_kernel(const int* __restrict__ dst, int* __restrict__ cnt, int E) {
    int e = blockIdx.x * blockDim.x + threadIdx.x;
    if (e < E) atomicAdd(&cnt[dst[e]], 1);
}

// single-block shuffle-based exclusive scan over n counts -> offs[0..n], cursor copy
__global__ void scan_kernel(const int* __restrict__ cnt, int* __restrict__ offs,
                            int* __restrict__ cursor, int n) {
    __shared__ int wsums[16];
    __shared__ int carry_s;
    int tid = threadIdx.x;          // 1024
    int lane = tid & 63, wid = tid >> 6;
    if (tid == 0) carry_s = 0;
    __syncthreads();
    for (int base = 0; base < n; base += 1024) {
        int i = base + tid;
        int v = (i < n) ? cnt[i] : 0;
        int x = v;
#pragma unroll
        for (int d = 1; d < 64; d <<= 1) {
            int t = __shfl_up(x, d, 64);
            if (lane >= d) x += t;
        }
        if (lane == 63) wsums[wid] = x;
        __syncthreads();
        if (wid == 0) {
            int s = (lane < 16) ? wsums[lane] : 0;
#pragma unroll
            for (int d = 1; d < 16; d <<= 1) {
                int t = __shfl_up(s, d, 64);
                if (lane >= d) s += t;
            }
            if (lane < 16) wsums[lane] = s;
        }
        __syncthreads();
        int waveoff = (wid > 0) ? wsums[wid - 1] : 0;
        int incl = carry_s + waveoff + x;
        if (i < n) { offs[i] = incl - v; cursor[i] = incl - v; }
        __syncthreads();            // everyone done reading carry_s
        if (tid == 1023) carry_s = incl;   // inclusive total through this chunk
        __syncthreads();
    }
    if (tid == 0) offs[n] = carry_s;
}

__global__ void dinv_kernel(const int* __restrict__ cnt, float* __restrict__ dinv, int n) {
    int i = blockIdx.x * blockDim.x + threadIdx.x;
    if (i < n) dinv[i] = 1.0f / sqrtf((float)cnt[i] + 1.0f);
}

__global__ void fill_csr_kernel(const int* __restrict__ src, const int* __restrict__ dst,
                                const float* __restrict__ dinv, int* __restrict__ cursor,
                                int* __restrict__ csr_src, float* __restrict__ csr_norm, int E) {
    int e = blockIdx.x * blockDim.x + threadIdx.x;
    if (e >= E) return;
    int s = src[e], d = dst[e];
    int pos = atomicAdd(&cursor[d], 1);
    csr_src[pos] = s;
    csr_norm[pos] = dinv[s] * dinv[d];
}

// ---------------- GEMMs (fp32 vector) ----------------

// x[n,11] @ W[11,128] -> out[n,128]; block=256 handles 2 nodes
__global__ void gemm_in_kernel(const float* __restrict__ x, const float* __restrict__ W,
                               float* __restrict__ out, int n) {
    __shared__ float Ws[F_IN * HIDDEN];
    __shared__ float xs[2][F_IN];
    int tid = threadIdx.x;
    for (int i = tid; i < F_IN * HIDDEN; i += 256) Ws[i] = W[i];
    if (tid < 2 * F_IN) {
        int r = tid / F_IN, c = tid % F_IN;
        long nn = (long)blockIdx.x * 2 + r;
        xs[r][c] = (nn < n) ? x[nn * F_IN + c] : 0.f;
    }
    __syncthreads();
    long node = (long)blockIdx.x * 2 + (tid >> 7);
    int f = tid & 127;
    int local = tid >> 7;
    if (node < n) {
        float acc = 0.f;
#pragma unroll
        for (int k = 0; k < F_IN; ++k) acc += xs[local][k] * Ws[k * HIDDEN + f];
        out[node * HIDDEN + f] = acc;
    }
}

// A[n,128] @ W[128,128] -> out[n,128]
// 256 threads, 64 nodes/block, K chunked x32, W-chunk + A-chunk in LDS,
// 8 nodes x 4 feats register tile per thread (32 acc VGPRs).
#define GM_NODES 64
__global__ void gemm128_kernel(const float* __restrict__ A, const float* __restrict__ W,
                               float* __restrict__ out, int n) {
    __shared__ float Ws[32][HIDDEN];   // 16 KB: W rows c*32..c*32+31
    __shared__ float As[GM_NODES][36]; // 9 KB: 64 nodes x 32 k (pad 36 for banks)
    int tid = threadIdx.x;
    long base = (long)blockIdx.x * GM_NODES;
    int fq = tid & 31;          // feature quad: feats fq*4..fq*4+3
    int nb = (tid >> 5) * 8;    // node base 0,8,..56

    float4 acc[8];
#pragma unroll
    for (int i = 0; i < 8; ++i) acc[i] = make_float4(0.f, 0.f, 0.f, 0.f);

    for (int c = 0; c < 4; ++c) {
        __syncthreads();        // previous chunk fully consumed
        // stage W chunk (rows c*32 .. c*32+31), coalesced float4, no transpose
#pragma unroll
        for (int r = 0; r < 4; ++r) {
            int idx = tid + 256 * r;       // 0..1023
            int k = idx >> 5, f4 = idx & 31;
            ((float4*)Ws[k])[f4] = ((const float4*)(W + (c * 32 + k) * HIDDEN))[f4];
        }
        // stage A chunk row-major: As[node][k0..k0+3]
#pragma unroll
        for (int r = 0; r < 2; ++r) {
            int idx = tid + 256 * r;       // 0..511
            int node = idx >> 3, kq = idx & 7;
            long gn = base + node;
            float4 a = (gn < n) ? ((const float4*)(A + gn * HIDDEN + c * 32))[kq]
                                : make_float4(0.f, 0.f, 0.f, 0.f);
            *(float4*)&As[node][kq * 4] = a;
        }
        __syncthreads();
#pragma unroll
        for (int k = 0; k < 32; ++k) {
            float4 w = ((float4*)Ws[k])[fq];
            float a0 = As[nb + 0][k], a1 = As[nb + 1][k];
            float a2 = As[nb + 2][k], a3 = As[nb + 3][k];
            float a4 = As[nb + 4][k], a5 = As[nb + 5][k];
            float a6 = As[nb + 6][k], a7 = As[nb + 7][k];
            acc[0].x += a0 * w.x; acc[0].y += a0 * w.y; acc[0].z += a0 * w.z; acc[0].w += a0 * w.w;
            acc[1].x += a1 * w.x; acc[1].y += a1 * w.y; acc[1].z += a1 * w.z; acc[1].w += a1 * w.w;
            acc[2].x += a2 * w.x; acc[2].y += a2 * w.y; acc[2].z += a2 * w.z; acc[2].w += a2 * w.w;
            acc[3].x += a3 * w.x; acc[3].y += a3 * w.y; acc[3].z += a3 * w.z; acc[3].w += a3 * w.w;
            acc[4].x += a4 * w.x; acc[4].y += a4 * w.y; acc[4].z += a4 * w.z; acc[4].w += a4 * w.w;
            acc[5].x += a5 * w.x; acc[5].y += a5 * w.y; acc[5].z += a5 * w.z; acc[5].w += a5 * w.w;
            acc[6].x += a6 * w.x; acc[6].y += a6 * w.y; acc[6].z += a6 * w.z; acc[6].w += a6 * w.w;
            acc[7].x += a7 * w.x; acc[7].y += a7 * w.y; acc[7].z += a7 * w.z; acc[7].w += a7 * w.w;
        }
    }
#pragma unroll
    for (int i = 0; i < 8; ++i) {
        long gn = base + nb + i;
        if (gn < n) ((float4*)(out + gn * HIDDEN))[fq] = acc[i];
    }
}

// ---------------- Aggregation (wave per node) ----------------

__global__ void agg_kernel(const float* __restrict__ h, const int* __restrict__ offs,
                           const int* __restrict__ csr_src, const float* __restrict__ csr_norm,
                           const float* __restrict__ dinv, const float* __restrict__ bias,
                           float* __restrict__ out, int n, int do_relu) {
    int node = (int)((blockIdx.x * (long)blockDim.x + threadIdx.x) >> 6);
    int lane = threadIdx.x & 63;
    if (node >= n) return;
    int beg = offs[node], end = offs[node + 1];
    float2 acc = {0.f, 0.f};
    for (int e = beg; e < end; ++e) {
        int s = csr_src[e];
        float w = csr_norm[e];
        float2 v = ((const float2*)(h + (long)s * HIDDEN))[lane];
        acc.x += w * v.x;
        acc.y += w * v.y;
    }
    float di = dinv[node];
    float sl = di * di;
    float2 hv = ((const float2*)(h + (long)node * HIDDEN))[lane];
    acc.x += sl * hv.x + bias[lane * 2];
    acc.y += sl * hv.y + bias[lane * 2 + 1];
    if (do_relu) { acc.x = fmaxf(acc.x, 0.f); acc.y = fmaxf(acc.y, 0.f); }
    ((float2*)(out + (long)node * HIDDEN))[lane] = acc;
}

// ---------------- Pool + head ----------------

__global__ void pool_kernel(const float* __restrict__ h, const int* __restrict__ batch,
                            float* __restrict__ pool, float* __restrict__ cnt, int n) {
    int node = (int)((blockIdx.x * (long)blockDim.x + threadIdx.x) >> 6);
    int lane = threadIdx.x & 63;
    if (node >= n) return;
    int g = batch[node];
    float2 v = ((const float2*)(h + (long)node * HIDDEN))[lane];
    atomicAdd(pool + (long)g * HIDDEN + lane * 2, v.x);
    atomicAdd(pool + (long)g * HIDDEN + lane * 2 + 1, v.y);
    if (lane == 0) atomicAdd(cnt + g, 1.0f);
}

__global__ void final_kernel(const float* __restrict__ pool, const float* __restrict__ cnt,
                             const float* __restrict__ Wl, const float* __restrict__ bl,
                             float* __restrict__ out, int G) {
    __shared__ float ps[HIDDEN];
    int g = blockIdx.x;
    int tid = threadIdx.x; // 64
    float inv = 1.0f / fmaxf(cnt[g], 1.0f);
    ps[tid] = pool[(long)g * HIDDEN + tid] * inv;
    ps[tid + 64] = pool[(long)g * HIDDEN + tid + 64] * inv;
    __syncthreads();
    if (tid < NCLS) {
        float acc = bl[tid];
#pragma unroll 8
        for (int k = 0; k < HIDDEN; ++k) acc += ps[k] * Wl[k * NCLS + tid];
        out[(long)g * NCLS + tid] = acc;
    }
}

// ---------------- launch ----------------

static inline size_t align256(size_t x) { return (x + 255) & ~(size_t)255; }

extern "C" void kernel_launch(void* const* d_in, const int* in_sizes, int n_in,
                              void* d_out, int out_size, void* d_ws, size_t ws_size,
                              hipStream_t stream) {
    const float* x    = (const float*)d_in[0];
    const int*   ei   = (const int*)d_in[1];
    const int*   batch= (const int*)d_in[2];
    const float* W1   = (const float*)d_in[3];
    const float* b1   = (const float*)d_in[4];
    const float* W2   = (const float*)d_in[5];
    const float* b2   = (const float*)d_in[6];
    const float* W3   = (const float*)d_in[7];
    const float* b3   = (const float*)d_in[8];
    const float* Wl   = (const float*)d_in[9];
    const float* bl   = (const float*)d_in[10];
    float* out = (float*)d_out;

    const int N = in_sizes[0] / F_IN;
    const int E = in_sizes[1] / 2;
    const int G = out_size / NCLS;
    const int* src = ei;
    const int* dst = ei + E;

    // workspace carve-up
    char* p = (char*)d_ws;
    size_t off = 0;
    int*   deg_cnt  = (int*)(p + off);  off = align256(off + (size_t)N * 4);
    int*   offs     = (int*)(p + off);  off = align256(off + (size_t)(N + 1) * 4);
    int*   cursor   = (int*)(p + off);  off = align256(off + (size_t)N * 4);
    float* dinv     = (float*)(p + off);off = align256(off + (size_t)N * 4);
    int*   csr_src  = (int*)(p + off);  off = align256(off + (size_t)E * 4);
    float* csr_norm = (float*)(p + off);off = align256(off + (size_t)E * 4);
    float* pool     = (float*)(p + off);off = align256(off + (size_t)G * (HIDDEN + 1) * 4);
    float* gcnt     = pool + (size_t)G * HIDDEN;
    float* h_a      = (float*)(p + off);off = align256(off + (size_t)N * HIDDEN * 4);
    float* h_b      = (float*)(p + off);off = align256(off + (size_t)N * HIDDEN * 4);
    (void)ws_size; (void)n_in;

    // zero the accumulated regions (ws is re-poisoned 0xAA before every call)
    hipMemsetAsync(deg_cnt, 0, (size_t)N * 4, stream);
    hipMemsetAsync(pool, 0, (size_t)G * (HIDDEN + 1) * 4, stream);

    // CSR build
    count_kernel<<<(E + 255) / 256, 256, 0, stream>>>(dst, deg_cnt, E);
    scan_kernel<<<1, 1024, 0, stream>>>(deg_cnt, offs, cursor, N);
    dinv_kernel<<<(N + 255) / 256, 256, 0, stream>>>(deg_cnt, dinv, N);
    fill_csr_kernel<<<(E + 255) / 256, 256, 0, stream>>>(src, dst, dinv, cursor,
                                                         csr_src, csr_norm, E);

    const int aggBlocks = (N + 3) / 4;  // 4 waves/block, wave per node
    const int gemmBlocks = (N + GM_NODES - 1) / GM_NODES;

    // layer 1: x@W1 -> h_a ; agg -> h_b (relu)
    gemm_in_kernel<<<(N + 1) / 2, 256, 0, stream>>>(x, W1, h_a, N);
    agg_kernel<<<aggBlocks, 256, 0, stream>>>(h_a, offs, csr_src, csr_norm, dinv, b1, h_b, N, 1);

    // layer 2: h_b@W2 -> h_a ; agg -> h_b (relu)
    gemm128_kernel<<<gemmBlocks, 256, 0, stream>>>(h_b, W2, h_a, N);
    agg_kernel<<<aggBlocks, 256, 0, stream>>>(h_a, offs, csr_src, csr_norm, dinv, b2, h_b, N, 1);

    // layer 3: h_b@W3 -> h_a ; agg -> h_b (no relu)
    gemm128_kernel<<<gemmBlocks, 256, 0, stream>>>(h_b, W3, h_a, N);
    agg_kernel<<<aggBlocks, 256, 0, stream>>>(h_a, offs, csr_src, csr_norm, dinv, b3, h_b, N, 0);

    // mean pool + head
    pool_kernel<<<aggBlocks, 256, 0, stream>>>(h_b, batch, pool, gcnt, N);
    final_kernel<<<G, 64, 0, stream>>>(pool, gcnt, Wl, bl, out, G);
}

// Round 3
// 488.918 us; speedup vs baseline: 1.6232x; 1.2965x over previous
//
#include <hip/hip_runtime.h>
#include <hip/hip_bf16.h>

// GCN2: 3x GCNConv(relu,relu,none) + global_mean_pool + linear head.
// R3: algebraic reorder. Layer1: z=N*x (16-padded, 64B/edge) then GEMM.
// Layer3+pool+head folded: out = P*N*(h2@(W3@Wl)) + (b3@Wl+bl) -> 19-wide agg.
// Layer2 agg stays 128-wide but 4-edge unrolled for memory-level parallelism.

#define HIDDEN 128
#define F_IN 11
#define NCLS 19

// ---------------- CSR build ----------------

__global__ void count_kernel(const int* __restrict__ dst, int* __restrict__ cnt, int E) {
    int e = blockIdx.x * blockDim.x + threadIdx.x;
    if (e < E) atomicAdd(&cnt[dst[e]], 1);
}

// single-block shuffle-based exclusive scan over n counts -> offs[0..n], cursor copy
__global__ void scan_kernel(const int* __restrict__ cnt, int* __restrict__ offs,
                            int* __restrict__ cursor, int n) {
    __shared__ int wsums[16];
    __shared__ int carry_s;
    int tid = threadIdx.x;          // 1024
    int lane = tid & 63, wid = tid >> 6;
    if (tid == 0) carry_s = 0;
    __syncthreads();
    for (int base = 0; base < n; base += 1024) {
        int i = base + tid;
        int v = (i < n) ? cnt[i] : 0;
        int x = v;
#pragma unroll
        for (int d = 1; d < 64; d <<= 1) {
            int t = __shfl_up(x, d, 64);
            if (lane >= d) x += t;
        }
        if (lane == 63) wsums[wid] = x;
        __syncthreads();
        if (wid == 0) {
            int s = (lane < 16) ? wsums[lane] : 0;
#pragma unroll
            for (int d = 1; d < 16; d <<= 1) {
                int t = __shfl_up(s, d, 64);
                if (lane >= d) s += t;
            }
            if (lane < 16) wsums[lane] = s;
        }
        __syncthreads();
        int waveoff = (wid > 0) ? wsums[wid - 1] : 0;
        int incl = carry_s + waveoff + x;
        if (i < n) { offs[i] = incl - v; cursor[i] = incl - v; }
        __syncthreads();
        if (tid == 1023) carry_s = incl;
        __syncthreads();
    }
    if (tid == 0) offs[n] = carry_s;
}

__global__ void dinv_kernel(const int* __restrict__ cnt, float* __restrict__ dinv, int n) {
    int i = blockIdx.x * blockDim.x + threadIdx.x;
    if (i < n) dinv[i] = 1.0f / sqrtf((float)cnt[i] + 1.0f);
}

__global__ void fill_csr_kernel(const int* __restrict__ src, const int* __restrict__ dst,
                                const float* __restrict__ dinv, int* __restrict__ cursor,
                                int* __restrict__ csr_src, float* __restrict__ csr_norm, int E) {
    int e = blockIdx.x * blockDim.x + threadIdx.x;
    if (e >= E) return;
    int s = src[e], d = dst[e];
    int pos = atomicAdd(&cursor[d], 1);
    csr_src[pos] = s;
    csr_norm[pos] = dinv[s] * dinv[d];
}

// ---------------- layer 1: pad x to 16, aggregate 16-wide, then GEMM ----------------

__global__ void pad_x16_kernel(const float* __restrict__ x, float* __restrict__ x16, int n) {
    long i = (long)blockIdx.x * blockDim.x + threadIdx.x;
    if (i >= (long)n * 16) return;
    int node = (int)(i >> 4), f = (int)(i & 15);
    x16[i] = (f < F_IN) ? x[(long)node * F_IN + f] : 0.f;
}

// wave per node, 4 edge-groups x 16 lanes; z16 = N_mat * x16
__global__ void agg16_kernel(const float* __restrict__ x16, const int* __restrict__ offs,
                             const int* __restrict__ csr_src, const float* __restrict__ csr_norm,
                             const float* __restrict__ dinv, float* __restrict__ z16, int n) {
    int node = (int)(((long)blockIdx.x * blockDim.x + threadIdx.x) >> 6);
    int lane = threadIdx.x & 63;
    if (node >= n) return;
    int grp = lane >> 4, f = lane & 15;
    int beg = offs[node], end = offs[node + 1];
    float acc = 0.f;
    for (int e = beg + grp; e < end; e += 4) {
        int s = csr_src[e];
        float w = csr_norm[e];
        acc += w * x16[(long)s * 16 + f];
    }
    acc += __shfl_down(acc, 32);
    acc += __shfl_down(acc, 16);
    if (grp == 0) {
        float di = dinv[node];
        z16[(long)node * 16 + f] = acc + di * di * x16[(long)node * 16 + f];
    }
}

// h1 = relu(z16[:, :11] @ W1 + b1); 8 nodes per 256-thread block
__global__ void gemm_in_kernel(const float* __restrict__ z16, const float* __restrict__ W1,
                               const float* __restrict__ b1, float* __restrict__ out, int n) {
    __shared__ float Ws[F_IN * HIDDEN];
    __shared__ float bs[HIDDEN];
    __shared__ float zs[8][16];
    int tid = threadIdx.x;
    long base = (long)blockIdx.x * 8;
    for (int i = tid; i < F_IN * HIDDEN; i += 256) Ws[i] = W1[i];
    if (tid < HIDDEN) bs[tid] = b1[tid];
    if (tid < 128) {
        int ln = tid >> 4, f = tid & 15;
        long gn = base + ln;
        zs[ln][f] = (gn < n) ? z16[gn * 16 + f] : 0.f;
    }
    __syncthreads();
    int f = tid & 127, half = tid >> 7;
#pragma unroll
    for (int r = 0; r < 4; ++r) {
        int ln = half * 4 + r;
        long gn = base + ln;
        float acc = bs[f];
#pragma unroll
        for (int k = 0; k < F_IN; ++k) acc += zs[ln][k] * Ws[k * HIDDEN + f];
        if (gn < n) out[gn * HIDDEN + f] = fmaxf(acc, 0.f);
    }
}

// ---------------- 128x128 GEMM (layer 2) ----------------

#define GM_NODES 64
__global__ void gemm128_kernel(const float* __restrict__ A, const float* __restrict__ W,
                               float* __restrict__ out, int n) {
    __shared__ float Ws[32][HIDDEN];
    __shared__ float As[GM_NODES][36];
    int tid = threadIdx.x;
    long base = (long)blockIdx.x * GM_NODES;
    int fq = tid & 31;
    int nb = (tid >> 5) * 8;

    float4 acc[8];
#pragma unroll
    for (int i = 0; i < 8; ++i) acc[i] = make_float4(0.f, 0.f, 0.f, 0.f);

    for (int c = 0; c < 4; ++c) {
        __syncthreads();
#pragma unroll
        for (int r = 0; r < 4; ++r) {
            int idx = tid + 256 * r;
            int k = idx >> 5, f4 = idx & 31;
            ((float4*)Ws[k])[f4] = ((const float4*)(W + (c * 32 + k) * HIDDEN))[f4];
        }
#pragma unroll
        for (int r = 0; r < 2; ++r) {
            int idx = tid + 256 * r;
            int node = idx >> 3, kq = idx & 7;
            long gn = base + node;
            float4 a = (gn < n) ? ((const float4*)(A + gn * HIDDEN + c * 32))[kq]
                                : make_float4(0.f, 0.f, 0.f, 0.f);
            *(float4*)&As[node][kq * 4] = a;
        }
        __syncthreads();
#pragma unroll
        for (int k = 0; k < 32; ++k) {
            float4 w = ((float4*)Ws[k])[fq];
            float a0 = As[nb + 0][k], a1 = As[nb + 1][k];
            float a2 = As[nb + 2][k], a3 = As[nb + 3][k];
            float a4 = As[nb + 4][k], a5 = As[nb + 5][k];
            float a6 = As[nb + 6][k], a7 = As[nb + 7][k];
            acc[0].x += a0 * w.x; acc[0].y += a0 * w.y; acc[0].z += a0 * w.z; acc[0].w += a0 * w.w;
            acc[1].x += a1 * w.x; acc[1].y += a1 * w.y; acc[1].z += a1 * w.z; acc[1].w += a1 * w.w;
            acc[2].x += a2 * w.x; acc[2].y += a2 * w.y; acc[2].z += a2 * w.z; acc[2].w += a2 * w.w;
            acc[3].x += a3 * w.x; acc[3].y += a3 * w.y; acc[3].z += a3 * w.z; acc[3].w += a3 * w.w;
            acc[4].x += a4 * w.x; acc[4].y += a4 * w.y; acc[4].z += a4 * w.z; acc[4].w += a4 * w.w;
            acc[5].x += a5 * w.x; acc[5].y += a5 * w.y; acc[5].z += a5 * w.z; acc[5].w += a5 * w.w;
            acc[6].x += a6 * w.x; acc[6].y += a6 * w.y; acc[6].z += a6 * w.z; acc[6].w += a6 * w.w;
            acc[7].x += a7 * w.x; acc[7].y += a7 * w.y; acc[7].z += a7 * w.z; acc[7].w += a7 * w.w;
        }
    }
#pragma unroll
    for (int i = 0; i < 8; ++i) {
        long gn = base + nb + i;
        if (gn < n) ((float4*)(out + gn * HIDDEN))[fq] = acc[i];
    }
}

// ---------------- 128-wide aggregation (layer 2), 4-edge unrolled ----------------

__global__ void agg_kernel(const float* __restrict__ h, const int* __restrict__ offs,
                           const int* __restrict__ csr_src, const float* __restrict__ csr_norm,
                           const float* __restrict__ dinv, const float* __restrict__ bias,
                           float* __restrict__ out, int n, int do_relu) {
    int node = (int)(((long)blockIdx.x * blockDim.x + threadIdx.x) >> 6);
    int lane = threadIdx.x & 63;
    if (node >= n) return;
    int beg = offs[node], end = offs[node + 1];
    float2 acc = {0.f, 0.f};
    int e = beg;
    int stop4 = beg + ((end - beg) & ~3);
    for (; e < stop4; e += 4) {
        int s0 = csr_src[e], s1 = csr_src[e + 1], s2 = csr_src[e + 2], s3 = csr_src[e + 3];
        float w0 = csr_norm[e], w1 = csr_norm[e + 1], w2 = csr_norm[e + 2], w3 = csr_norm[e + 3];
        float2 v0 = ((const float2*)(h + (long)s0 * HIDDEN))[lane];
        float2 v1 = ((const float2*)(h + (long)s1 * HIDDEN))[lane];
        float2 v2 = ((const float2*)(h + (long)s2 * HIDDEN))[lane];
        float2 v3 = ((const float2*)(h + (long)s3 * HIDDEN))[lane];
        acc.x += w0 * v0.x + w1 * v1.x + w2 * v2.x + w3 * v3.x;
        acc.y += w0 * v0.y + w1 * v1.y + w2 * v2.y + w3 * v3.y;
    }
    for (; e < end; ++e) {
        int s = csr_src[e];
        float w = csr_norm[e];
        float2 v = ((const float2*)(h + (long)s * HIDDEN))[lane];
        acc.x += w * v.x;
        acc.y += w * v.y;
    }
    float di = dinv[node];
    float sl = di * di;
    float2 hv = ((const float2*)(h + (long)node * HIDDEN))[lane];
    acc.x += sl * hv.x + bias[lane * 2];
    acc.y += sl * hv.y + bias[lane * 2 + 1];
    if (do_relu) { acc.x = fmaxf(acc.x, 0.f); acc.y = fmaxf(acc.y, 0.f); }
    ((float2*)(out + (long)node * HIDDEN))[lane] = acc;
}

// ---------------- folded layer 3 + pool + head ----------------

// W3l = W3 @ Wl [128,19]; b3l = b3 @ Wl [19] (bl added in final)
__global__ void w3l_kernel(const float* __restrict__ W3, const float* __restrict__ Wl,
                           const float* __restrict__ b3, float* __restrict__ W3l,
                           float* __restrict__ b3l) {
    int tid = threadIdx.x;
    for (int o = tid; o < HIDDEN * NCLS; o += 256) {
        int i = o / NCLS, j = o % NCLS;
        float acc = 0.f;
#pragma unroll 8
        for (int k = 0; k < HIDDEN; ++k) acc += W3[i * HIDDEN + k] * Wl[k * NCLS + j];
        W3l[o] = acc;
    }
    if (tid < NCLS) {
        float acc = 0.f;
#pragma unroll 8
        for (int k = 0; k < HIDDEN; ++k) acc += b3[k] * Wl[k * NCLS + tid];
        b3l[tid] = acc;
    }
}

// y24[n,24] (first 19 cols valid) = h2 @ W3l; 12 nodes per 256-thread block
__global__ void gemm_y24_kernel(const float* __restrict__ h2, const float* __restrict__ W3l,
                                float* __restrict__ y24, int n) {
    __shared__ float hs[12][HIDDEN];
    __shared__ float Ws[HIDDEN][20];
    int tid = threadIdx.x;
    long base = (long)blockIdx.x * 12;
    for (int i = tid; i < HIDDEN * NCLS; i += 256) Ws[i / NCLS][i % NCLS] = W3l[i];
    for (int idx = tid; idx < 12 * 32; idx += 256) {
        int node = idx >> 5, q = idx & 31;
        long gn = base + node;
        float4 a = (gn < n) ? ((const float4*)(h2 + gn * HIDDEN))[q]
                            : make_float4(0.f, 0.f, 0.f, 0.f);
        *(float4*)&hs[node][q * 4] = a;
    }
    __syncthreads();
    if (tid < 12 * NCLS) {
        int node = tid / NCLS, j = tid % NCLS;
        long gn = base + node;
        float acc = 0.f;
#pragma unroll 8
        for (int k = 0; k < HIDDEN; ++k) acc += hs[node][k] * Ws[k][j];
        if (gn < n) y24[gn * 24 + j] = acc;
    }
}

// z3 = N_mat * y24 (19 valid cols), fused with mean-pool atomics.
// wave per node, 2 edge-groups x 32 lanes (19 active per group).
__global__ void agg24_pool_kernel(const float* __restrict__ y24, const int* __restrict__ offs,
                                  const int* __restrict__ csr_src, const float* __restrict__ csr_norm,
                                  const float* __restrict__ dinv, const int* __restrict__ batch,
                                  float* __restrict__ pool, float* __restrict__ cnt, int n) {
    int node = (int)(((long)blockIdx.x * blockDim.x + threadIdx.x) >> 6);
    int lane = threadIdx.x & 63;
    if (node >= n) return;
    int grp = lane >> 5, f = lane & 31;
    int beg = offs[node], end = offs[node + 1];
    float acc = 0.f;
    int e = beg + grp;
    for (; e + 2 < end; e += 4) {
        int s0 = csr_src[e], s1 = csr_src[e + 2];
        float w0 = csr_norm[e], w1 = csr_norm[e + 2];
        float v0 = (f < NCLS) ? y24[(long)s0 * 24 + f] : 0.f;
        float v1 = (f < NCLS) ? y24[(long)s1 * 24 + f] : 0.f;
        acc += w0 * v0 + w1 * v1;
    }
    for (; e < end; e += 2) {
        int s = csr_src[e];
        float w = csr_norm[e];
        float v = (f < NCLS) ? y24[(long)s * 24 + f] : 0.f;
        acc += w * v;
    }
    acc += __shfl_down(acc, 32);
    int g = batch[node];
    if (grp == 0 && f < NCLS) {
        float di = dinv[node];
        float z = acc + di * di * y24[(long)node * 24 + f];
        atomicAdd(&pool[(long)g * NCLS + f], z);
    }
    if (lane == 0) atomicAdd(&cnt[g], 1.f);
}

__global__ void final_kernel(const float* __restrict__ pool, const float* __restrict__ cnt,
                             const float* __restrict__ b3l, const float* __restrict__ bl,
                             float* __restrict__ out, int G) {
    int i = blockIdx.x * blockDim.x + threadIdx.x;
    if (i >= G * NCLS) return;
    int g = i / NCLS, j = i % NCLS;
    float c = cnt[g];
    out[i] = (c > 0.f) ? pool[i] / c + b3l[j] + bl[j] : bl[j];
}

// ---------------- launch ----------------

static inline size_t align256(size_t x) { return (x + 255) & ~(size_t)255; }

extern "C" void kernel_launch(void* const* d_in, const int* in_sizes, int n_in,
                              void* d_out, int out_size, void* d_ws, size_t ws_size,
                              hipStream_t stream) {
    const float* x    = (const float*)d_in[0];
    const int*   ei   = (const int*)d_in[1];
    const int*   batch= (const int*)d_in[2];
    const float* W1   = (const float*)d_in[3];
    const float* b1   = (const float*)d_in[4];
    const float* W2   = (const float*)d_in[5];
    const float* b2   = (const float*)d_in[6];
    const float* W3   = (const float*)d_in[7];
    const float* b3   = (const float*)d_in[8];
    const float* Wl   = (const float*)d_in[9];
    const float* bl   = (const float*)d_in[10];
    float* out = (float*)d_out;

    const int N = in_sizes[0] / F_IN;
    const int E = in_sizes[1] / 2;
    const int G = out_size / NCLS;
    const int* src = ei;
    const int* dst = ei + E;

    // workspace carve-up
    char* p = (char*)d_ws;
    size_t off = 0;
    int*   deg_cnt  = (int*)(p + off);  off = align256(off + (size_t)N * 4);
    int*   offs     = (int*)(p + off);  off = align256(off + (size_t)(N + 1) * 4);
    int*   cursor   = (int*)(p + off);  off = align256(off + (size_t)N * 4);
    float* dinv     = (float*)(p + off);off = align256(off + (size_t)N * 4);
    int*   csr_src  = (int*)(p + off);  off = align256(off + (size_t)E * 4);
    float* csr_norm = (float*)(p + off);off = align256(off + (size_t)E * 4);
    float* x16      = (float*)(p + off);off = align256(off + (size_t)N * 16 * 4);
    float* z16      = (float*)(p + off);off = align256(off + (size_t)N * 16 * 4);
    float* y24      = (float*)(p + off);off = align256(off + (size_t)N * 24 * 4);
    float* W3l      = (float*)(p + off);off = align256(off + (size_t)HIDDEN * NCLS * 4);
    float* b3l      = (float*)(p + off);off = align256(off + (size_t)NCLS * 4);
    float* pool     = (float*)(p + off);off = align256(off + (size_t)G * (NCLS + 1) * 4);
    float* gcnt     = pool + (size_t)G * NCLS;
    float* h_a      = (float*)(p + off);off = align256(off + (size_t)N * HIDDEN * 4);
    float* h_b      = (float*)(p + off);off = align256(off + (size_t)N * HIDDEN * 4);
    (void)ws_size; (void)n_in;

    hipMemsetAsync(deg_cnt, 0, (size_t)N * 4, stream);
    hipMemsetAsync(pool, 0, (size_t)G * (NCLS + 1) * 4, stream);

    // CSR build
    count_kernel<<<(E + 255) / 256, 256, 0, stream>>>(dst, deg_cnt, E);
    scan_kernel<<<1, 1024, 0, stream>>>(deg_cnt, offs, cursor, N);
    dinv_kernel<<<(N + 255) / 256, 256, 0, stream>>>(deg_cnt, dinv, N);
    fill_csr_kernel<<<(E + 255) / 256, 256, 0, stream>>>(src, dst, dinv, cursor,
                                                         csr_src, csr_norm, E);
    // tiny precompute (independent of CSR)
    w3l_kernel<<<1, 256, 0, stream>>>(W3, Wl, b3, W3l, b3l);

    const int aggBlocks = (N + 3) / 4;  // 4 waves/block, wave per node

    // layer 1 (reordered): z16 = N*x16 ; h1 = relu(z16@W1+b1) -> h_a
    pad_x16_kernel<<<(N * 16 + 255) / 256, 256, 0, stream>>>(x, x16, N);
    agg16_kernel<<<aggBlocks, 256, 0, stream>>>(x16, offs, csr_src, csr_norm, dinv, z16, N);
    gemm_in_kernel<<<(N + 7) / 8, 256, 0, stream>>>(z16, W1, b1, h_a, N);

    // layer 2: g1 = h1@W2 -> h_b ; h2 = relu(N*g1+b2) -> h_a
    gemm128_kernel<<<(N + GM_NODES - 1) / GM_NODES, 256, 0, stream>>>(h_a, W2, h_b, N);
    agg_kernel<<<aggBlocks, 256, 0, stream>>>(h_b, offs, csr_src, csr_norm, dinv, b2, h_a, N, 1);

    // folded layer 3 + pool: y24 = h2@W3l ; pool += N*y24 per graph
    gemm_y24_kernel<<<(N + 11) / 12, 256, 0, stream>>>(h_a, W3l, y24, N);
    agg24_pool_kernel<<<aggBlocks, 256, 0, stream>>>(y24, offs, csr_src, csr_norm, dinv,
                                                     batch, pool, gcnt, N);
    final_kernel<<<(G * NCLS + 255) / 256, 256, 0, stream>>>(pool, gcnt, b3l, bl, out, G);
}

// Round 4
// 471.675 us; speedup vs baseline: 1.6825x; 1.0366x over previous
//
#include <hip/hip_runtime.h>
#include <hip/hip_bf16.h>

// GCN2: 3x GCNConv(relu,relu,none) + global_mean_pool + linear head.
// R4: gather sources pre-scaled by dinv (norm = dinv[d]*dinv[s] factored),
// self-loops inserted as CSR edges (csr_src only, 4B/edge), and all agg
// kernels use explicit 8-deep register load pipelines for MLP (R3's loops
// were compiler-serialized: VGPR_Count=12 -> latency-bound at 672 GB/s).

#define HIDDEN 128
#define F_IN 11
#define NCLS 19

// ---------------- CSR build ----------------

__global__ void count_kernel(const int* __restrict__ dst, int* __restrict__ cnt, int E) {
    int e = blockIdx.x * blockDim.x + threadIdx.x;
    if (e < E) atomicAdd(&cnt[dst[e]], 1);
}

// single-block shuffle-based exclusive scan over (cnt[i]+1) -> offs[0..n], cursor copy
// (+1 = self-loop slot per node)
__global__ void scan_kernel(const int* __restrict__ cnt, int* __restrict__ offs,
                            int* __restrict__ cursor, int n) {
    __shared__ int wsums[16];
    __shared__ int carry_s;
    int tid = threadIdx.x;          // 1024
    int lane = tid & 63, wid = tid >> 6;
    if (tid == 0) carry_s = 0;
    __syncthreads();
    for (int base = 0; base < n; base += 1024) {
        int i = base + tid;
        int v = (i < n) ? cnt[i] + 1 : 0;
        int x = v;
#pragma unroll
        for (int d = 1; d < 64; d <<= 1) {
            int t = __shfl_up(x, d, 64);
            if (lane >= d) x += t;
        }
        if (lane == 63) wsums[wid] = x;
        __syncthreads();
        if (wid == 0) {
            int s = (lane < 16) ? wsums[lane] : 0;
#pragma unroll
            for (int d = 1; d < 16; d <<= 1) {
                int t = __shfl_up(s, d, 64);
                if (lane >= d) s += t;
            }
            if (lane < 16) wsums[lane] = s;
        }
        __syncthreads();
        int waveoff = (wid > 0) ? wsums[wid - 1] : 0;
        int incl = carry_s + waveoff + x;
        if (i < n) { offs[i] = incl - v; cursor[i] = incl - v; }
        __syncthreads();
        if (tid == 1023) carry_s = incl;
        __syncthreads();
    }
    if (tid == 0) offs[n] = carry_s;
}

// dinv + self-edge insertion + per-graph node count
__global__ void dinv_self_kernel(const int* __restrict__ cnt, int* __restrict__ cursor,
                                 int* __restrict__ csr_src, float* __restrict__ dinv,
                                 const int* __restrict__ batch, float* __restrict__ gcnt,
                                 int n) {
    int i = blockIdx.x * blockDim.x + threadIdx.x;
    if (i >= n) return;
    dinv[i] = 1.0f / sqrtf((float)cnt[i] + 1.0f);
    int pos = atomicAdd(&cursor[i], 1);
    csr_src[pos] = i;
    atomicAdd(&gcnt[batch[i]], 1.0f);
}

__global__ void fill_csr_kernel(const int* __restrict__ src, const int* __restrict__ dst,
                                int* __restrict__ cursor, int* __restrict__ csr_src, int E) {
    int e = blockIdx.x * blockDim.x + threadIdx.x;
    if (e >= E) return;
    int pos = atomicAdd(&cursor[dst[e]], 1);
    csr_src[pos] = src[e];
}

// ---------------- layer 1: pad+scale x to 16, aggregate 16-wide, GEMM ----------------

__global__ void pad_x16_kernel(const float* __restrict__ x, const float* __restrict__ dinv,
                               float* __restrict__ x16, int n) {
    long i = (long)blockIdx.x * blockDim.x + threadIdx.x;
    if (i >= (long)n * 16) return;
    int node = (int)(i >> 4), f = (int)(i & 15);
    x16[i] = (f < F_IN) ? x[(long)node * F_IN + f] * dinv[node] : 0.f;
}

// wave per node, 4 groups x 16 lanes, 8-deep pipeline per group
__global__ void agg16_kernel(const float* __restrict__ xs, const int* __restrict__ offs,
                             const int* __restrict__ csr_src, const float* __restrict__ dinv,
                             float* __restrict__ z16, int n) {
    int node = (int)(((long)blockIdx.x * blockDim.x + threadIdx.x) >> 6);
    int lane = threadIdx.x & 63;
    if (node >= n) return;
    int grp = lane >> 4, f = lane & 15;
    int beg = offs[node], end = offs[node + 1];
    float acc = 0.f;
    int eb = beg;
    for (; eb + 32 <= end; eb += 32) {
        int s[8]; float v[8];
#pragma unroll
        for (int j = 0; j < 8; ++j) s[j] = csr_src[eb + grp + 4 * j];
#pragma unroll
        for (int j = 0; j < 8; ++j) v[j] = xs[(long)s[j] * 16 + f];
#pragma unroll
        for (int j = 0; j < 8; ++j) acc += v[j];
    }
    for (int e = eb + grp; e < end; e += 4)
        acc += xs[(long)csr_src[e] * 16 + f];
    acc += __shfl_down(acc, 32);
    acc += __shfl_down(acc, 16);
    if (lane < 16) z16[(long)node * 16 + lane] = acc * dinv[node];
}

// h1 = relu(z16[:, :11] @ W1 + b1); 8 nodes per 256-thread block
__global__ void gemm_in_kernel(const float* __restrict__ z16, const float* __restrict__ W1,
                               const float* __restrict__ b1, float* __restrict__ out, int n) {
    __shared__ float Ws[F_IN * HIDDEN];
    __shared__ float bs[HIDDEN];
    __shared__ float zs[8][16];
    int tid = threadIdx.x;
    long base = (long)blockIdx.x * 8;
    for (int i = tid; i < F_IN * HIDDEN; i += 256) Ws[i] = W1[i];
    if (tid < HIDDEN) bs[tid] = b1[tid];
    if (tid < 128) {
        int ln = tid >> 4, f = tid & 15;
        long gn = base + ln;
        zs[ln][f] = (gn < n) ? z16[gn * 16 + f] : 0.f;
    }
    __syncthreads();
    int f = tid & 127, half = tid >> 7;
#pragma unroll
    for (int r = 0; r < 4; ++r) {
        int ln = half * 4 + r;
        long gn = base + ln;
        float acc = bs[f];
#pragma unroll
        for (int k = 0; k < F_IN; ++k) acc += zs[ln][k] * Ws[k * HIDDEN + f];
        if (gn < n) out[gn * HIDDEN + f] = fmaxf(acc, 0.f);
    }
}

// ---------------- 128x128 GEMM (layer 2), output rows scaled by dinv ----------------

#define GM_NODES 64
__global__ void gemm128_kernel(const float* __restrict__ A, const float* __restrict__ W,
                               const float* __restrict__ dinv, float* __restrict__ out, int n) {
    __shared__ float Ws[32][HIDDEN];
    __shared__ float As[GM_NODES][36];
    int tid = threadIdx.x;
    long base = (long)blockIdx.x * GM_NODES;
    int fq = tid & 31;
    int nb = (tid >> 5) * 8;

    float4 acc[8];
#pragma unroll
    for (int i = 0; i < 8; ++i) acc[i] = make_float4(0.f, 0.f, 0.f, 0.f);

    for (int c = 0; c < 4; ++c) {
        __syncthreads();
#pragma unroll
        for (int r = 0; r < 4; ++r) {
            int idx = tid + 256 * r;
            int k = idx >> 5, f4 = idx & 31;
            ((float4*)Ws[k])[f4] = ((const float4*)(W + (c * 32 + k) * HIDDEN))[f4];
        }
#pragma unroll
        for (int r = 0; r < 2; ++r) {
            int idx = tid + 256 * r;
            int node = idx >> 3, kq = idx & 7;
            long gn = base + node;
            float4 a = (gn < n) ? ((const float4*)(A + gn * HIDDEN + c * 32))[kq]
                                : make_float4(0.f, 0.f, 0.f, 0.f);
            *(float4*)&As[node][kq * 4] = a;
        }
        __syncthreads();
#pragma unroll
        for (int k = 0; k < 32; ++k) {
            float4 w = ((float4*)Ws[k])[fq];
            float a0 = As[nb + 0][k], a1 = As[nb + 1][k];
            float a2 = As[nb + 2][k], a3 = As[nb + 3][k];
            float a4 = As[nb + 4][k], a5 = As[nb + 5][k];
            float a6 = As[nb + 6][k], a7 = As[nb + 7][k];
            acc[0].x += a0 * w.x; acc[0].y += a0 * w.y; acc[0].z += a0 * w.z; acc[0].w += a0 * w.w;
            acc[1].x += a1 * w.x; acc[1].y += a1 * w.y; acc[1].z += a1 * w.z; acc[1].w += a1 * w.w;
            acc[2].x += a2 * w.x; acc[2].y += a2 * w.y; acc[2].z += a2 * w.z; acc[2].w += a2 * w.w;
            acc[3].x += a3 * w.x; acc[3].y += a3 * w.y; acc[3].z += a3 * w.z; acc[3].w += a3 * w.w;
            acc[4].x += a4 * w.x; acc[4].y += a4 * w.y; acc[4].z += a4 * w.z; acc[4].w += a4 * w.w;
            acc[5].x += a5 * w.x; acc[5].y += a5 * w.y; acc[5].z += a5 * w.z; acc[5].w += a5 * w.w;
            acc[6].x += a6 * w.x; acc[6].y += a6 * w.y; acc[6].z += a6 * w.z; acc[6].w += a6 * w.w;
            acc[7].x += a7 * w.x; acc[7].y += a7 * w.y; acc[7].z += a7 * w.z; acc[7].w += a7 * w.w;
        }
    }
#pragma unroll
    for (int i = 0; i < 8; ++i) {
        long gn = base + nb + i;
        if (gn < n) {
            float di = dinv[gn];
            acc[i].x *= di; acc[i].y *= di; acc[i].z *= di; acc[i].w *= di;
            ((float4*)(out + gn * HIDDEN))[fq] = acc[i];
        }
    }
}

// ---------------- 128-wide aggregation (layer 2), 8-deep pipeline ----------------

__global__ void agg128_kernel(const float* __restrict__ hs, const int* __restrict__ offs,
                              const int* __restrict__ csr_src, const float* __restrict__ dinv,
                              const float* __restrict__ bias, float* __restrict__ out, int n) {
    int node = (int)(((long)blockIdx.x * blockDim.x + threadIdx.x) >> 6);
    int lane = threadIdx.x & 63;
    if (node >= n) return;
    int beg = offs[node], end = offs[node + 1];
    float2 acc = {0.f, 0.f};
    int e = beg;
    for (; e + 8 <= end; e += 8) {
        int s[8]; float2 v[8];
#pragma unroll
        for (int j = 0; j < 8; ++j) s[j] = csr_src[e + j];
#pragma unroll
        for (int j = 0; j < 8; ++j) v[j] = ((const float2*)(hs + (long)s[j] * HIDDEN))[lane];
#pragma unroll
        for (int j = 0; j < 8; ++j) { acc.x += v[j].x; acc.y += v[j].y; }
    }
    if (e + 4 <= end) {
        int s[4]; float2 v[4];
#pragma unroll
        for (int j = 0; j < 4; ++j) s[j] = csr_src[e + j];
#pragma unroll
        for (int j = 0; j < 4; ++j) v[j] = ((const float2*)(hs + (long)s[j] * HIDDEN))[lane];
#pragma unroll
        for (int j = 0; j < 4; ++j) { acc.x += v[j].x; acc.y += v[j].y; }
        e += 4;
    }
    for (; e < end; ++e) {
        float2 v = ((const float2*)(hs + (long)csr_src[e] * HIDDEN))[lane];
        acc.x += v.x; acc.y += v.y;
    }
    float di = dinv[node];
    acc.x = fmaxf(acc.x * di + bias[lane * 2], 0.f);
    acc.y = fmaxf(acc.y * di + bias[lane * 2 + 1], 0.f);
    ((float2*)(out + (long)node * HIDDEN))[lane] = acc;
}

// ---------------- folded layer 3 + pool + head ----------------

__global__ void w3l_kernel(const float* __restrict__ W3, const float* __restrict__ Wl,
                           const float* __restrict__ b3, float* __restrict__ W3l,
                           float* __restrict__ b3l) {
    int tid = threadIdx.x;
    for (int o = tid; o < HIDDEN * NCLS; o += 256) {
        int i = o / NCLS, j = o % NCLS;
        float acc = 0.f;
#pragma unroll 8
        for (int k = 0; k < HIDDEN; ++k) acc += W3[i * HIDDEN + k] * Wl[k * NCLS + j];
        W3l[o] = acc;
    }
    if (tid < NCLS) {
        float acc = 0.f;
#pragma unroll 8
        for (int k = 0; k < HIDDEN; ++k) acc += b3[k] * Wl[k * NCLS + tid];
        b3l[tid] = acc;
    }
}

// y24[n,24] = (h2 @ W3l) * dinv[row], cols 19..23 zeroed; 12 nodes/block
__global__ void gemm_y24_kernel(const float* __restrict__ h2, const float* __restrict__ W3l,
                                const float* __restrict__ dinv, float* __restrict__ y24, int n) {
    __shared__ float hs[12][HIDDEN];
    __shared__ float Ws[HIDDEN][20];
    int tid = threadIdx.x;
    long base = (long)blockIdx.x * 12;
    for (int i = tid; i < HIDDEN * NCLS; i += 256) Ws[i / NCLS][i % NCLS] = W3l[i];
    for (int idx = tid; idx < 12 * 32; idx += 256) {
        int node = idx >> 5, q = idx & 31;
        long gn = base + node;
        float4 a = (gn < n) ? ((const float4*)(h2 + gn * HIDDEN))[q]
                            : make_float4(0.f, 0.f, 0.f, 0.f);
        *(float4*)&hs[node][q * 4] = a;
    }
    __syncthreads();
    if (tid < 12 * NCLS) {
        int node = tid / NCLS, j = tid % NCLS;
        long gn = base + node;
        if (gn < n) {
            float acc = 0.f;
#pragma unroll 8
            for (int k = 0; k < HIDDEN; ++k) acc += hs[node][k] * Ws[k][j];
            y24[gn * 24 + j] = acc * dinv[gn];
        }
    }
    for (int idx = tid; idx < 12 * 5; idx += 256) {
        int node = idx / 5, j = 19 + idx % 5;
        long gn = base + node;
        if (gn < n) y24[gn * 24 + j] = 0.f;
    }
}

// pool[g] += dinv[d] * sum_{e in N(d) U {d}} y24s[src_e]; wave/node, 2 grp x 32, 8-deep
__global__ void agg24_pool_kernel(const float* __restrict__ ys, const int* __restrict__ offs,
                                  const int* __restrict__ csr_src, const float* __restrict__ dinv,
                                  const int* __restrict__ batch, float* __restrict__ pool, int n) {
    int node = (int)(((long)blockIdx.x * blockDim.x + threadIdx.x) >> 6);
    int lane = threadIdx.x & 63;
    if (node >= n) return;
    int grp = lane >> 5, f = lane & 31;
    int beg = offs[node], end = offs[node + 1];
    float acc = 0.f;
    int eb = beg;
    bool fok = (f < 24);
    for (; eb + 16 <= end; eb += 16) {
        int s[8]; float v[8];
#pragma unroll
        for (int j = 0; j < 8; ++j) s[j] = csr_src[eb + grp + 2 * j];
#pragma unroll
        for (int j = 0; j < 8; ++j) v[j] = fok ? ys[(long)s[j] * 24 + f] : 0.f;
#pragma unroll
        for (int j = 0; j < 8; ++j) acc += v[j];
    }
    for (int e = eb + grp; e < end; e += 2)
        acc += fok ? ys[(long)csr_src[e] * 24 + f] : 0.f;
    acc += __shfl_down(acc, 32);
    if (lane < NCLS) {
        int g = batch[node];
        atomicAdd(&pool[(long)g * 24 + lane], acc * dinv[node]);
    }
}

__global__ void final_kernel(const float* __restrict__ pool, const float* __restrict__ cnt,
                             const float* __restrict__ b3l, const float* __restrict__ bl,
                             float* __restrict__ out, int G) {
    int i = blockIdx.x * blockDim.x + threadIdx.x;
    if (i >= G * NCLS) return;
    int g = i / NCLS, j = i % NCLS;
    float c = cnt[g];
    out[i] = (c > 0.f) ? pool[(long)g * 24 + j] / c + b3l[j] + bl[j] : bl[j];
}

// ---------------- launch ----------------

static inline size_t align256(size_t x) { return (x + 255) & ~(size_t)255; }

extern "C" void kernel_launch(void* const* d_in, const int* in_sizes, int n_in,
                              void* d_out, int out_size, void* d_ws, size_t ws_size,
                              hipStream_t stream) {
    const float* x    = (const float*)d_in[0];
    const int*   ei   = (const int*)d_in[1];
    const int*   batch= (const int*)d_in[2];
    const float* W1   = (const float*)d_in[3];
    const float* b1   = (const float*)d_in[4];
    const float* W2   = (const float*)d_in[5];
    const float* b2   = (const float*)d_in[6];
    const float* W3   = (const float*)d_in[7];
    const float* b3   = (const float*)d_in[8];
    const float* Wl   = (const float*)d_in[9];
    const float* bl   = (const float*)d_in[10];
    float* out = (float*)d_out;

    const int N = in_sizes[0] / F_IN;
    const int E = in_sizes[1] / 2;
    const int G = out_size / NCLS;
    const int* src = ei;
    const int* dst = ei + E;

    // workspace carve-up
    char* p = (char*)d_ws;
    size_t off = 0;
    int*   deg_cnt  = (int*)(p + off);  off = align256(off + (size_t)N * 4);
    int*   offs     = (int*)(p + off);  off = align256(off + (size_t)(N + 1) * 4);
    int*   cursor   = (int*)(p + off);  off = align256(off + (size_t)N * 4);
    float* dinv     = (float*)(p + off);off = align256(off + (size_t)N * 4);
    int*   csr_src  = (int*)(p + off);  off = align256(off + (size_t)(E + N) * 4);
    float* x16      = (float*)(p + off);off = align256(off + (size_t)N * 16 * 4);
    float* z16      = (float*)(p + off);off = align256(off + (size_t)N * 16 * 4);
    float* y24      = (float*)(p + off);off = align256(off + (size_t)N * 24 * 4);
    float* W3l      = (float*)(p + off);off = align256(off + (size_t)HIDDEN * NCLS * 4);
    float* b3l      = (float*)(p + off);off = align256(off + (size_t)NCLS * 4);
    float* pool     = (float*)(p + off);off = align256(off + (size_t)G * 25 * 4);
    float* gcnt     = pool + (size_t)G * 24;
    float* h_a      = (float*)(p + off);off = align256(off + (size_t)N * HIDDEN * 4);
    float* h_b      = (float*)(p + off);off = align256(off + (size_t)N * HIDDEN * 4);
    (void)ws_size; (void)n_in;

    hipMemsetAsync(deg_cnt, 0, (size_t)N * 4, stream);
    hipMemsetAsync(pool, 0, (size_t)G * 25 * 4, stream);

    // CSR build (with self-loops)
    count_kernel<<<(E + 255) / 256, 256, 0, stream>>>(dst, deg_cnt, E);
    scan_kernel<<<1, 1024, 0, stream>>>(deg_cnt, offs, cursor, N);
    dinv_self_kernel<<<(N + 255) / 256, 256, 0, stream>>>(deg_cnt, cursor, csr_src, dinv,
                                                          batch, gcnt, N);
    fill_csr_kernel<<<(E + 255) / 256, 256, 0, stream>>>(src, dst, cursor, csr_src, E);
    w3l_kernel<<<1, 256, 0, stream>>>(W3, Wl, b3, W3l, b3l);

    const int aggBlocks = (N + 3) / 4;  // 4 waves/block, wave per node

    // layer 1: z16 = dinv * N_sum(x*dinv) ; h1 = relu(z16@W1+b1) -> h_a
    pad_x16_kernel<<<(N * 16 + 255) / 256, 256, 0, stream>>>(x, dinv, x16, N);
    agg16_kernel<<<aggBlocks, 256, 0, stream>>>(x16, offs, csr_src, dinv, z16, N);
    gemm_in_kernel<<<(N + 7) / 8, 256, 0, stream>>>(z16, W1, b1, h_a, N);

    // layer 2: hs = (h1@W2)*dinv -> h_b ; h2 = relu(dinv*sum hs + b2) -> h_a
    gemm128_kernel<<<(N + GM_NODES - 1) / GM_NODES, 256, 0, stream>>>(h_a, W2, dinv, h_b, N);
    agg128_kernel<<<aggBlocks, 256, 0, stream>>>(h_b, offs, csr_src, dinv, b2, h_a, N);

    // folded layer 3 + pool
    gemm_y24_kernel<<<(N + 11) / 12, 256, 0, stream>>>(h_a, W3l, dinv, y24, N);
    agg24_pool_kernel<<<aggBlocks, 256, 0, stream>>>(y24, offs, csr_src, dinv, batch, pool, N);
    final_kernel<<<(G * NCLS + 255) / 256, 256, 0, stream>>>(pool, gcnt, b3l, bl, out, G);
}

// Round 5
// 412.687 us; speedup vs baseline: 1.9230x; 1.1429x over previous
//
#include <hip/hip_runtime.h>
#include <hip/hip_bf16.h>

// GCN2: 3x GCNConv(relu,relu,none) + global_mean_pool + linear head.
// R5: w3l_kernel was 60us on ONE block -> multi-block (11 blocks, Wl in LDS).
// agg128 -> 2 edge-groups x 32 lanes x float4, 8-deep per group (16 rows in
// flight/wave). agg16/agg24 pipelines resized to engage at avg degree ~17.

#define HIDDEN 128
#define F_IN 11
#define NCLS 19

// ---------------- CSR build ----------------

__global__ void count_kernel(const int* __restrict__ dst, int* __restrict__ cnt, int E) {
    int e = blockIdx.x * blockDim.x + threadIdx.x;
    if (e < E) atomicAdd(&cnt[dst[e]], 1);
}

// single-block shuffle-based exclusive scan over (cnt[i]+1) -> offs[0..n], cursor copy
__global__ void scan_kernel(const int* __restrict__ cnt, int* __restrict__ offs,
                            int* __restrict__ cursor, int n) {
    __shared__ int wsums[16];
    __shared__ int carry_s;
    int tid = threadIdx.x;          // 1024
    int lane = tid & 63, wid = tid >> 6;
    if (tid == 0) carry_s = 0;
    __syncthreads();
    for (int base = 0; base < n; base += 1024) {
        int i = base + tid;
        int v = (i < n) ? cnt[i] + 1 : 0;
        int x = v;
#pragma unroll
        for (int d = 1; d < 64; d <<= 1) {
            int t = __shfl_up(x, d, 64);
            if (lane >= d) x += t;
        }
        if (lane == 63) wsums[wid] = x;
        __syncthreads();
        if (wid == 0) {
            int s = (lane < 16) ? wsums[lane] : 0;
#pragma unroll
            for (int d = 1; d < 16; d <<= 1) {
                int t = __shfl_up(s, d, 64);
                if (lane >= d) s += t;
            }
            if (lane < 16) wsums[lane] = s;
        }
        __syncthreads();
        int waveoff = (wid > 0) ? wsums[wid - 1] : 0;
        int incl = carry_s + waveoff + x;
        if (i < n) { offs[i] = incl - v; cursor[i] = incl - v; }
        __syncthreads();
        if (tid == 1023) carry_s = incl;
        __syncthreads();
    }
    if (tid == 0) offs[n] = carry_s;
}

// dinv + self-edge insertion + per-graph node count
__global__ void dinv_self_kernel(const int* __restrict__ cnt, int* __restrict__ cursor,
                                 int* __restrict__ csr_src, float* __restrict__ dinv,
                                 const int* __restrict__ batch, float* __restrict__ gcnt,
                                 int n) {
    int i = blockIdx.x * blockDim.x + threadIdx.x;
    if (i >= n) return;
    dinv[i] = 1.0f / sqrtf((float)cnt[i] + 1.0f);
    int pos = atomicAdd(&cursor[i], 1);
    csr_src[pos] = i;
    atomicAdd(&gcnt[batch[i]], 1.0f);
}

__global__ void fill_csr_kernel(const int* __restrict__ src, const int* __restrict__ dst,
                                int* __restrict__ cursor, int* __restrict__ csr_src, int E) {
    int e = blockIdx.x * blockDim.x + threadIdx.x;
    if (e >= E) return;
    int pos = atomicAdd(&cursor[dst[e]], 1);
    csr_src[pos] = src[e];
}

// ---------------- layer 1: pad+scale x to 16, aggregate 16-wide, GEMM ----------------

__global__ void pad_x16_kernel(const float* __restrict__ x, const float* __restrict__ dinv,
                               float* __restrict__ x16, int n) {
    long i = (long)blockIdx.x * blockDim.x + threadIdx.x;
    if (i >= (long)n * 16) return;
    int node = (int)(i >> 4), f = (int)(i & 15);
    x16[i] = (f < F_IN) ? x[(long)node * F_IN + f] * dinv[node] : 0.f;
}

// wave per node, 4 groups x 16 lanes; chunks of 16/8 edges, then tail
__global__ void agg16_kernel(const float* __restrict__ xs, const int* __restrict__ offs,
                             const int* __restrict__ csr_src, const float* __restrict__ dinv,
                             float* __restrict__ z16, int n) {
    int node = (int)(((long)blockIdx.x * blockDim.x + threadIdx.x) >> 6);
    int lane = threadIdx.x & 63;
    if (node >= n) return;
    int grp = lane >> 4, f = lane & 15;
    int beg = offs[node], end = offs[node + 1];
    float acc = 0.f;
    int eb = beg;
    for (; eb + 16 <= end; eb += 16) {
        int s[4]; float v[4];
#pragma unroll
        for (int j = 0; j < 4; ++j) s[j] = csr_src[eb + grp + 4 * j];
#pragma unroll
        for (int j = 0; j < 4; ++j) v[j] = xs[(long)s[j] * 16 + f];
#pragma unroll
        for (int j = 0; j < 4; ++j) acc += v[j];
    }
    if (eb + 8 <= end) {
        int s[2]; float v[2];
#pragma unroll
        for (int j = 0; j < 2; ++j) s[j] = csr_src[eb + grp + 4 * j];
#pragma unroll
        for (int j = 0; j < 2; ++j) v[j] = xs[(long)s[j] * 16 + f];
        acc += v[0] + v[1];
        eb += 8;
    }
    for (int e = eb + grp; e < end; e += 4)
        acc += xs[(long)csr_src[e] * 16 + f];
    acc += __shfl_down(acc, 32);
    acc += __shfl_down(acc, 16);
    if (lane < 16) z16[(long)node * 16 + lane] = acc * dinv[node];
}

// h1 = relu(z16[:, :11] @ W1 + b1); 8 nodes per 256-thread block
__global__ void gemm_in_kernel(const float* __restrict__ z16, const float* __restrict__ W1,
                               const float* __restrict__ b1, float* __restrict__ out, int n) {
    __shared__ float Ws[F_IN * HIDDEN];
    __shared__ float bs[HIDDEN];
    __shared__ float zs[8][16];
    int tid = threadIdx.x;
    long base = (long)blockIdx.x * 8;
    for (int i = tid; i < F_IN * HIDDEN; i += 256) Ws[i] = W1[i];
    if (tid < HIDDEN) bs[tid] = b1[tid];
    if (tid < 128) {
        int ln = tid >> 4, f = tid & 15;
        long gn = base + ln;
        zs[ln][f] = (gn < n) ? z16[gn * 16 + f] : 0.f;
    }
    __syncthreads();
    int f = tid & 127, half = tid >> 7;
#pragma unroll
    for (int r = 0; r < 4; ++r) {
        int ln = half * 4 + r;
        long gn = base + ln;
        float acc = bs[f];
#pragma unroll
        for (int k = 0; k < F_IN; ++k) acc += zs[ln][k] * Ws[k * HIDDEN + f];
        if (gn < n) out[gn * HIDDEN + f] = fmaxf(acc, 0.f);
    }
}

// ---------------- 128x128 GEMM (layer 2), output rows scaled by dinv ----------------

#define GM_NODES 64
__global__ void gemm128_kernel(const float* __restrict__ A, const float* __restrict__ W,
                               const float* __restrict__ dinv, float* __restrict__ out, int n) {
    __shared__ float Ws[32][HIDDEN];
    __shared__ float As[GM_NODES][36];
    int tid = threadIdx.x;
    long base = (long)blockIdx.x * GM_NODES;
    int fq = tid & 31;
    int nb = (tid >> 5) * 8;

    float4 acc[8];
#pragma unroll
    for (int i = 0; i < 8; ++i) acc[i] = make_float4(0.f, 0.f, 0.f, 0.f);

    for (int c = 0; c < 4; ++c) {
        __syncthreads();
#pragma unroll
        for (int r = 0; r < 4; ++r) {
            int idx = tid + 256 * r;
            int k = idx >> 5, f4 = idx & 31;
            ((float4*)Ws[k])[f4] = ((const float4*)(W + (c * 32 + k) * HIDDEN))[f4];
        }
#pragma unroll
        for (int r = 0; r < 2; ++r) {
            int idx = tid + 256 * r;
            int node = idx >> 3, kq = idx & 7;
            long gn = base + node;
            float4 a = (gn < n) ? ((const float4*)(A + gn * HIDDEN + c * 32))[kq]
                                : make_float4(0.f, 0.f, 0.f, 0.f);
            *(float4*)&As[node][kq * 4] = a;
        }
        __syncthreads();
#pragma unroll
        for (int k = 0; k < 32; ++k) {
            float4 w = ((float4*)Ws[k])[fq];
            float a0 = As[nb + 0][k], a1 = As[nb + 1][k];
            float a2 = As[nb + 2][k], a3 = As[nb + 3][k];
            float a4 = As[nb + 4][k], a5 = As[nb + 5][k];
            float a6 = As[nb + 6][k], a7 = As[nb + 7][k];
            acc[0].x += a0 * w.x; acc[0].y += a0 * w.y; acc[0].z += a0 * w.z; acc[0].w += a0 * w.w;
            acc[1].x += a1 * w.x; acc[1].y += a1 * w.y; acc[1].z += a1 * w.z; acc[1].w += a1 * w.w;
            acc[2].x += a2 * w.x; acc[2].y += a2 * w.y; acc[2].z += a2 * w.z; acc[2].w += a2 * w.w;
            acc[3].x += a3 * w.x; acc[3].y += a3 * w.y; acc[3].z += a3 * w.z; acc[3].w += a3 * w.w;
            acc[4].x += a4 * w.x; acc[4].y += a4 * w.y; acc[4].z += a4 * w.z; acc[4].w += a4 * w.w;
            acc[5].x += a5 * w.x; acc[5].y += a5 * w.y; acc[5].z += a5 * w.z; acc[5].w += a5 * w.w;
            acc[6].x += a6 * w.x; acc[6].y += a6 * w.y; acc[6].z += a6 * w.z; acc[6].w += a6 * w.w;
            acc[7].x += a7 * w.x; acc[7].y += a7 * w.y; acc[7].z += a7 * w.z; acc[7].w += a7 * w.w;
        }
    }
#pragma unroll
    for (int i = 0; i < 8; ++i) {
        long gn = base + nb + i;
        if (gn < n) {
            float di = dinv[gn];
            acc[i].x *= di; acc[i].y *= di; acc[i].z *= di; acc[i].w *= di;
            ((float4*)(out + gn * HIDDEN))[fq] = acc[i];
        }
    }
}

// ---------------- 128-wide aggregation: 2 groups x 32 lanes x float4 ----------------

__global__ void agg128_kernel(const float* __restrict__ hs, const int* __restrict__ offs,
                              const int* __restrict__ csr_src, const float* __restrict__ dinv,
                              const float* __restrict__ bias, float* __restrict__ out, int n) {
    int node = (int)(((long)blockIdx.x * blockDim.x + threadIdx.x) >> 6);
    int lane = threadIdx.x & 63;
    if (node >= n) return;
    int grp = lane >> 5, q = lane & 31;
    int beg = offs[node], end = offs[node + 1];
    float4 acc = make_float4(0.f, 0.f, 0.f, 0.f);
    int eb = beg;
    for (; eb + 16 <= end; eb += 16) {
        int s[8]; float4 v[8];
#pragma unroll
        for (int j = 0; j < 8; ++j) s[j] = csr_src[eb + grp + 2 * j];
#pragma unroll
        for (int j = 0; j < 8; ++j) v[j] = ((const float4*)(hs + (long)s[j] * HIDDEN))[q];
#pragma unroll
        for (int j = 0; j < 8; ++j) {
            acc.x += v[j].x; acc.y += v[j].y; acc.z += v[j].z; acc.w += v[j].w;
        }
    }
    if (eb + 8 <= end) {
        int s[4]; float4 v[4];
#pragma unroll
        for (int j = 0; j < 4; ++j) s[j] = csr_src[eb + grp + 2 * j];
#pragma unroll
        for (int j = 0; j < 4; ++j) v[j] = ((const float4*)(hs + (long)s[j] * HIDDEN))[q];
#pragma unroll
        for (int j = 0; j < 4; ++j) {
            acc.x += v[j].x; acc.y += v[j].y; acc.z += v[j].z; acc.w += v[j].w;
        }
        eb += 8;
    }
    for (int e = eb + grp; e < end; e += 2) {
        float4 v = ((const float4*)(hs + (long)csr_src[e] * HIDDEN))[q];
        acc.x += v.x; acc.y += v.y; acc.z += v.z; acc.w += v.w;
    }
    acc.x += __shfl_down(acc.x, 32);
    acc.y += __shfl_down(acc.y, 32);
    acc.z += __shfl_down(acc.z, 32);
    acc.w += __shfl_down(acc.w, 32);
    if (grp == 0) {
        float di = dinv[node];
        float4 b = ((const float4*)bias)[q];
        acc.x = fmaxf(acc.x * di + b.x, 0.f);
        acc.y = fmaxf(acc.y * di + b.y, 0.f);
        acc.z = fmaxf(acc.z * di + b.z, 0.f);
        acc.w = fmaxf(acc.w * di + b.w, 0.f);
        ((float4*)(out + (long)node * HIDDEN))[q] = acc;
    }
}

// ---------------- folded layer 3 + pool + head ----------------

// W3l = W3@Wl [128,19], b3l = b3@Wl [19]; multi-block, Wl staged in LDS
__global__ void w3l_kernel(const float* __restrict__ W3, const float* __restrict__ Wl,
                           const float* __restrict__ b3, float* __restrict__ W3l,
                           float* __restrict__ b3l) {
    __shared__ float Wls[HIDDEN * NCLS];
    int tid = threadIdx.x;
    for (int i = tid; i < HIDDEN * NCLS; i += 256) Wls[i] = Wl[i];
    __syncthreads();
    if (blockIdx.x < 10) {
        int o = blockIdx.x * 256 + tid;
        if (o < HIDDEN * NCLS) {
            int i = o / NCLS, j = o % NCLS;
            float acc = 0.f;
#pragma unroll 8
            for (int k = 0; k < HIDDEN; ++k) acc += W3[i * HIDDEN + k] * Wls[k * NCLS + j];
            W3l[o] = acc;
        }
    } else if (tid < NCLS) {
        float acc = 0.f;
#pragma unroll 8
        for (int k = 0; k < HIDDEN; ++k) acc += b3[k] * Wls[k * NCLS + tid];
        b3l[tid] = acc;
    }
}

// y24[n,24] = (h2 @ W3l) * dinv[row], cols 19..23 zeroed; 12 nodes/block
__global__ void gemm_y24_kernel(const float* __restrict__ h2, const float* __restrict__ W3l,
                                const float* __restrict__ dinv, float* __restrict__ y24, int n) {
    __shared__ float hs[12][HIDDEN];
    __shared__ float Ws[HIDDEN][20];
    int tid = threadIdx.x;
    long base = (long)blockIdx.x * 12;
    for (int i = tid; i < HIDDEN * NCLS; i += 256) Ws[i / NCLS][i % NCLS] = W3l[i];
    for (int idx = tid; idx < 12 * 32; idx += 256) {
        int node = idx >> 5, q = idx & 31;
        long gn = base + node;
        float4 a = (gn < n) ? ((const float4*)(h2 + gn * HIDDEN))[q]
                            : make_float4(0.f, 0.f, 0.f, 0.f);
        *(float4*)&hs[node][q * 4] = a;
    }
    __syncthreads();
    if (tid < 12 * NCLS) {
        int node = tid / NCLS, j = tid % NCLS;
        long gn = base + node;
        if (gn < n) {
            float acc = 0.f;
#pragma unroll 8
            for (int k = 0; k < HIDDEN; ++k) acc += hs[node][k] * Ws[k][j];
            y24[gn * 24 + j] = acc * dinv[gn];
        }
    }
    for (int idx = tid; idx < 12 * 5; idx += 256) {
        int node = idx / 5, j = 19 + idx % 5;
        long gn = base + node;
        if (gn < n) y24[gn * 24 + j] = 0.f;
    }
}

// pool[g] += dinv[d] * sum_{e} ys[src_e]; wave/node, 2 grp x 32, 8/4-deep
__global__ void agg24_pool_kernel(const float* __restrict__ ys, const int* __restrict__ offs,
                                  const int* __restrict__ csr_src, const float* __restrict__ dinv,
                                  const int* __restrict__ batch, float* __restrict__ pool, int n) {
    int node = (int)(((long)blockIdx.x * blockDim.x + threadIdx.x) >> 6);
    int lane = threadIdx.x & 63;
    if (node >= n) return;
    int grp = lane >> 5, f = lane & 31;
    int beg = offs[node], end = offs[node + 1];
    float acc = 0.f;
    int eb = beg;
    bool fok = (f < 24);
    for (; eb + 16 <= end; eb += 16) {
        int s[8]; float v[8];
#pragma unroll
        for (int j = 0; j < 8; ++j) s[j] = csr_src[eb + grp + 2 * j];
#pragma unroll
        for (int j = 0; j < 8; ++j) v[j] = fok ? ys[(long)s[j] * 24 + f] : 0.f;
#pragma unroll
        for (int j = 0; j < 8; ++j) acc += v[j];
    }
    if (eb + 8 <= end) {
        int s[4]; float v[4];
#pragma unroll
        for (int j = 0; j < 4; ++j) s[j] = csr_src[eb + grp + 2 * j];
#pragma unroll
        for (int j = 0; j < 4; ++j) v[j] = fok ? ys[(long)s[j] * 24 + f] : 0.f;
#pragma unroll
        for (int j = 0; j < 4; ++j) acc += v[j];
        eb += 8;
    }
    for (int e = eb + grp; e < end; e += 2)
        acc += fok ? ys[(long)csr_src[e] * 24 + f] : 0.f;
    acc += __shfl_down(acc, 32);
    if (lane < NCLS) {
        int g = batch[node];
        atomicAdd(&pool[(long)g * 24 + lane], acc * dinv[node]);
    }
}

__global__ void final_kernel(const float* __restrict__ pool, const float* __restrict__ cnt,
                             const float* __restrict__ b3l, const float* __restrict__ bl,
                             float* __restrict__ out, int G) {
    int i = blockIdx.x * blockDim.x + threadIdx.x;
    if (i >= G * NCLS) return;
    int g = i / NCLS, j = i % NCLS;
    float c = cnt[g];
    out[i] = (c > 0.f) ? pool[(long)g * 24 + j] / c + b3l[j] + bl[j] : bl[j];
}

// ---------------- launch ----------------

static inline size_t align256(size_t x) { return (x + 255) & ~(size_t)255; }

extern "C" void kernel_launch(void* const* d_in, const int* in_sizes, int n_in,
                              void* d_out, int out_size, void* d_ws, size_t ws_size,
                              hipStream_t stream) {
    const float* x    = (const float*)d_in[0];
    const int*   ei   = (const int*)d_in[1];
    const int*   batch= (const int*)d_in[2];
    const float* W1   = (const float*)d_in[3];
    const float* b1   = (const float*)d_in[4];
    const float* W2   = (const float*)d_in[5];
    const float* b2   = (const float*)d_in[6];
    const float* W3   = (const float*)d_in[7];
    const float* b3   = (const float*)d_in[8];
    const float* Wl   = (const float*)d_in[9];
    const float* bl   = (const float*)d_in[10];
    float* out = (float*)d_out;

    const int N = in_sizes[0] / F_IN;
    const int E = in_sizes[1] / 2;
    const int G = out_size / NCLS;
    const int* src = ei;
    const int* dst = ei + E;

    // workspace carve-up
    char* p = (char*)d_ws;
    size_t off = 0;
    int*   deg_cnt  = (int*)(p + off);  off = align256(off + (size_t)N * 4);
    int*   offs     = (int*)(p + off);  off = align256(off + (size_t)(N + 1) * 4);
    int*   cursor   = (int*)(p + off);  off = align256(off + (size_t)N * 4);
    float* dinv     = (float*)(p + off);off = align256(off + (size_t)N * 4);
    int*   csr_src  = (int*)(p + off);  off = align256(off + (size_t)(E + N) * 4);
    float* x16      = (float*)(p + off);off = align256(off + (size_t)N * 16 * 4);
    float* z16      = (float*)(p + off);off = align256(off + (size_t)N * 16 * 4);
    float* y24      = (float*)(p + off);off = align256(off + (size_t)N * 24 * 4);
    float* W3l      = (float*)(p + off);off = align256(off + (size_t)HIDDEN * NCLS * 4);
    float* b3l      = (float*)(p + off);off = align256(off + (size_t)NCLS * 4);
    float* pool     = (float*)(p + off);off = align256(off + (size_t)G * 25 * 4);
    float* gcnt     = pool + (size_t)G * 24;
    float* h_a      = (float*)(p + off);off = align256(off + (size_t)N * HIDDEN * 4);
    float* h_b      = (float*)(p + off);off = align256(off + (size_t)N * HIDDEN * 4);
    (void)ws_size; (void)n_in;

    hipMemsetAsync(deg_cnt, 0, (size_t)N * 4, stream);
    hipMemsetAsync(pool, 0, (size_t)G * 25 * 4, stream);

    // CSR build (with self-loops)
    count_kernel<<<(E + 255) / 256, 256, 0, stream>>>(dst, deg_cnt, E);
    scan_kernel<<<1, 1024, 0, stream>>>(deg_cnt, offs, cursor, N);
    dinv_self_kernel<<<(N + 255) / 256, 256, 0, stream>>>(deg_cnt, cursor, csr_src, dinv,
                                                          batch, gcnt, N);
    fill_csr_kernel<<<(E + 255) / 256, 256, 0, stream>>>(src, dst, cursor, csr_src, E);
    w3l_kernel<<<11, 256, 0, stream>>>(W3, Wl, b3, W3l, b3l);

    const int aggBlocks = (N + 3) / 4;  // 4 waves/block, wave per node

    // layer 1: z16 = dinv * N_sum(x*dinv) ; h1 = relu(z16@W1+b1) -> h_a
    pad_x16_kernel<<<(N * 16 + 255) / 256, 256, 0, stream>>>(x, dinv, x16, N);
    agg16_kernel<<<aggBlocks, 256, 0, stream>>>(x16, offs, csr_src, dinv, z16, N);
    gemm_in_kernel<<<(N + 7) / 8, 256, 0, stream>>>(z16, W1, b1, h_a, N);

    // layer 2: hs = (h1@W2)*dinv -> h_b ; h2 = relu(dinv*sum hs + b2) -> h_a
    gemm128_kernel<<<(N + GM_NODES - 1) / GM_NODES, 256, 0, stream>>>(h_a, W2, dinv, h_b, N);
    agg128_kernel<<<aggBlocks, 256, 0, stream>>>(h_b, offs, csr_src, dinv, b2, h_a, N);

    // folded layer 3 + pool
    gemm_y24_kernel<<<(N + 11) / 12, 256, 0, stream>>>(h_a, W3l, dinv, y24, N);
    agg24_pool_kernel<<<aggBlocks, 256, 0, stream>>>(y24, offs, csr_src, dinv, batch, pool, N);
    final_kernel<<<(G * NCLS + 255) / 256, 256, 0, stream>>>(pool, gcnt, b3l, bl, out, G);
}

// Round 6
// 344.247 us; speedup vs baseline: 2.3053x; 1.1988x over previous
//
#include <hip/hip_runtime.h>
#include <hip/hip_bf16.h>
#include <hip/hip_fp16.h>

// GCN2: 3x GCNConv(relu,relu,none) + global_mean_pool + linear head.
// R6: agg128 hit a 3.7 TB/s random-gather BW wall (2x in-flight changed
// nothing) -> halve bytes: fp16 gather payloads (hs rows 256B / 12.8MB,
// y rows 64B / 3.2MB = L2-resident). Scan -> 3-phase multi-block, with
// dinv/self-edge/gcnt/x16-pad fused into the finalize pass.

#define HIDDEN 128
#define F_IN 11
#define NCLS 19

// ---------------- CSR build ----------------

__global__ void count_kernel(const int* __restrict__ dst, int* __restrict__ cnt, int E) {
    int e = blockIdx.x * blockDim.x + threadIdx.x;
    if (e < E) atomicAdd(&cnt[dst[e]], 1);
}

// phase A: per-block inclusive scan of v=cnt[i]+1; linc[i], btot[block]
__global__ void scanA_kernel(const int* __restrict__ cnt, int* __restrict__ linc,
                             int* __restrict__ btot, int n) {
    __shared__ int wsums[16];
    int tid = threadIdx.x;          // 1024
    int lane = tid & 63, wid = tid >> 6;
    int i = blockIdx.x * 1024 + tid;
    int v = (i < n) ? cnt[i] + 1 : 0;
    int x = v;
#pragma unroll
    for (int d = 1; d < 64; d <<= 1) {
        int t = __shfl_up(x, d, 64);
        if (lane >= d) x += t;
    }
    if (lane == 63) wsums[wid] = x;
    __syncthreads();
    if (wid == 0) {
        int s = (lane < 16) ? wsums[lane] : 0;
#pragma unroll
        for (int d = 1; d < 16; d <<= 1) {
            int t = __shfl_up(s, d, 64);
            if (lane >= d) s += t;
        }
        if (lane < 16) wsums[lane] = s;
    }
    __syncthreads();
    int incl = ((wid > 0) ? wsums[wid - 1] : 0) + x;
    if (i < n) linc[i] = incl;
    if (tid == 1023) btot[blockIdx.x] = incl;
}

// phase B: 1 block scans nblk block totals -> boff (exclusive); offs[n]=grand total
__global__ void scanB_kernel(const int* __restrict__ btot, int* __restrict__ boff,
                             int* __restrict__ offs, int n, int nblk) {
    __shared__ int wsums[16];
    int tid = threadIdx.x;          // 1024
    int lane = tid & 63, wid = tid >> 6;
    int v = (tid < nblk) ? btot[tid] : 0;
    int x = v;
#pragma unroll
    for (int d = 1; d < 64; d <<= 1) {
        int t = __shfl_up(x, d, 64);
        if (lane >= d) x += t;
    }
    if (lane == 63) wsums[wid] = x;
    __syncthreads();
    if (wid == 0) {
        int s = (lane < 16) ? wsums[lane] : 0;
#pragma unroll
        for (int d = 1; d < 16; d <<= 1) {
            int t = __shfl_up(s, d, 64);
            if (lane >= d) s += t;
        }
        if (lane < 16) wsums[lane] = s;
    }
    __syncthreads();
    int incl = ((wid > 0) ? wsums[wid - 1] : 0) + x;
    if (tid < nblk) boff[tid] = incl - v;
    if (tid == 1023) offs[n] = incl;
}

// phase C: finalize offs/cursor, self-edge first, dinv, gcnt, x16 pad+scale
__global__ void scanC_kernel(const int* __restrict__ cnt, const int* __restrict__ linc,
                             const int* __restrict__ boff, int* __restrict__ offs,
                             int* __restrict__ cursor, int* __restrict__ csr_src,
                             float* __restrict__ dinv, const int* __restrict__ batch,
                             float* __restrict__ gcnt, const float* __restrict__ x,
                             float* __restrict__ x16, int n) {
    int i = blockIdx.x * blockDim.x + threadIdx.x;
    if (i >= n) return;
    int v = cnt[i] + 1;
    int base = boff[i >> 10] + linc[i] - v;   // exclusive prefix
    offs[i] = base;
    csr_src[base] = i;                        // self-loop occupies slot 0
    cursor[i] = base + 1;
    float di = 1.0f / sqrtf((float)v);
    dinv[i] = di;
    atomicAdd(&gcnt[batch[i]], 1.0f);
#pragma unroll
    for (int j = 0; j < 16; ++j)
        x16[(long)i * 16 + j] = (j < F_IN) ? x[(long)i * F_IN + j] * di : 0.f;
}

__global__ void fill_csr_kernel(const int* __restrict__ src, const int* __restrict__ dst,
                                int* __restrict__ cursor, int* __restrict__ csr_src, int E) {
    int e = blockIdx.x * blockDim.x + threadIdx.x;
    if (e >= E) return;
    int pos = atomicAdd(&cursor[dst[e]], 1);
    csr_src[pos] = src[e];
}

// ---------------- layer 1 ----------------

// wave per node, 4 groups x 16 lanes; chunks of 16/8 edges, then tail
__global__ void agg16_kernel(const float* __restrict__ xs, const int* __restrict__ offs,
                             const int* __restrict__ csr_src, const float* __restrict__ dinv,
                             float* __restrict__ z16, int n) {
    int node = (int)(((long)blockIdx.x * blockDim.x + threadIdx.x) >> 6);
    int lane = threadIdx.x & 63;
    if (node >= n) return;
    int grp = lane >> 4, f = lane & 15;
    int beg = offs[node], end = offs[node + 1];
    float acc = 0.f;
    int eb = beg;
    for (; eb + 16 <= end; eb += 16) {
        int s[4]; float v[4];
#pragma unroll
        for (int j = 0; j < 4; ++j) s[j] = csr_src[eb + grp + 4 * j];
#pragma unroll
        for (int j = 0; j < 4; ++j) v[j] = xs[(long)s[j] * 16 + f];
#pragma unroll
        for (int j = 0; j < 4; ++j) acc += v[j];
    }
    if (eb + 8 <= end) {
        int s[2]; float v[2];
#pragma unroll
        for (int j = 0; j < 2; ++j) s[j] = csr_src[eb + grp + 4 * j];
#pragma unroll
        for (int j = 0; j < 2; ++j) v[j] = xs[(long)s[j] * 16 + f];
        acc += v[0] + v[1];
        eb += 8;
    }
    for (int e = eb + grp; e < end; e += 4)
        acc += xs[(long)csr_src[e] * 16 + f];
    acc += __shfl_down(acc, 32);
    acc += __shfl_down(acc, 16);
    if (lane < 16) z16[(long)node * 16 + lane] = acc * dinv[node];
}

// h1 = relu(z16[:, :11] @ W1 + b1); 8 nodes per 256-thread block
__global__ void gemm_in_kernel(const float* __restrict__ z16, const float* __restrict__ W1,
                               const float* __restrict__ b1, float* __restrict__ out, int n) {
    __shared__ float Ws[F_IN * HIDDEN];
    __shared__ float bs[HIDDEN];
    __shared__ float zs[8][16];
    int tid = threadIdx.x;
    long base = (long)blockIdx.x * 8;
    for (int i = tid; i < F_IN * HIDDEN; i += 256) Ws[i] = W1[i];
    if (tid < HIDDEN) bs[tid] = b1[tid];
    if (tid < 128) {
        int ln = tid >> 4, f = tid & 15;
        long gn = base + ln;
        zs[ln][f] = (gn < n) ? z16[gn * 16 + f] : 0.f;
    }
    __syncthreads();
    int f = tid & 127, half = tid >> 7;
#pragma unroll
    for (int r = 0; r < 4; ++r) {
        int ln = half * 4 + r;
        long gn = base + ln;
        float acc = bs[f];
#pragma unroll
        for (int k = 0; k < F_IN; ++k) acc += zs[ln][k] * Ws[k * HIDDEN + f];
        if (gn < n) out[gn * HIDDEN + f] = fmaxf(acc, 0.f);
    }
}

// ---------------- 128x128 GEMM (layer 2), half output scaled by dinv ----------------

#define GM_NODES 64
__global__ void gemm128h_kernel(const float* __restrict__ A, const float* __restrict__ W,
                                const float* __restrict__ dinv, __half* __restrict__ outh,
                                int n) {
    __shared__ float Ws[32][HIDDEN];
    __shared__ float As[GM_NODES][36];
    int tid = threadIdx.x;
    long base = (long)blockIdx.x * GM_NODES;
    int fq = tid & 31;
    int nb = (tid >> 5) * 8;

    float4 acc[8];
#pragma unroll
    for (int i = 0; i < 8; ++i) acc[i] = make_float4(0.f, 0.f, 0.f, 0.f);

    for (int c = 0; c < 4; ++c) {
        __syncthreads();
#pragma unroll
        for (int r = 0; r < 4; ++r) {
            int idx = tid + 256 * r;
            int k = idx >> 5, f4 = idx & 31;
            ((float4*)Ws[k])[f4] = ((const float4*)(W + (c * 32 + k) * HIDDEN))[f4];
        }
#pragma unroll
        for (int r = 0; r < 2; ++r) {
            int idx = tid + 256 * r;
            int node = idx >> 3, kq = idx & 7;
            long gn = base + node;
            float4 a = (gn < n) ? ((const float4*)(A + gn * HIDDEN + c * 32))[kq]
                                : make_float4(0.f, 0.f, 0.f, 0.f);
            *(float4*)&As[node][kq * 4] = a;
        }
        __syncthreads();
#pragma unroll
        for (int k = 0; k < 32; ++k) {
            float4 w = ((float4*)Ws[k])[fq];
            float a0 = As[nb + 0][k], a1 = As[nb + 1][k];
            float a2 = As[nb + 2][k], a3 = As[nb + 3][k];
            float a4 = As[nb + 4][k], a5 = As[nb + 5][k];
            float a6 = As[nb + 6][k], a7 = As[nb + 7][k];
            acc[0].x += a0 * w.x; acc[0].y += a0 * w.y; acc[0].z += a0 * w.z; acc[0].w += a0 * w.w;
            acc[1].x += a1 * w.x; acc[1].y += a1 * w.y; acc[1].z += a1 * w.z; acc[1].w += a1 * w.w;
            acc[2].x += a2 * w.x; acc[2].y += a2 * w.y; acc[2].z += a2 * w.z; acc[2].w += a2 * w.w;
            acc[3].x += a3 * w.x; acc[3].y += a3 * w.y; acc[3].z += a3 * w.z; acc[3].w += a3 * w.w;
            acc[4].x += a4 * w.x; acc[4].y += a4 * w.y; acc[4].z += a4 * w.z; acc[4].w += a4 * w.w;
            acc[5].x += a5 * w.x; acc[5].y += a5 * w.y; acc[5].z += a5 * w.z; acc[5].w += a5 * w.w;
            acc[6].x += a6 * w.x; acc[6].y += a6 * w.y; acc[6].z += a6 * w.z; acc[6].w += a6 * w.w;
            acc[7].x += a7 * w.x; acc[7].y += a7 * w.y; acc[7].z += a7 * w.z; acc[7].w += a7 * w.w;
        }
    }
#pragma unroll
    for (int i = 0; i < 8; ++i) {
        long gn = base + nb + i;
        if (gn < n) {
            float di = dinv[gn];
            __half2 h01 = __floats2half2_rn(acc[i].x * di, acc[i].y * di);
            __half2 h23 = __floats2half2_rn(acc[i].z * di, acc[i].w * di);
            uint2 u = make_uint2(*(unsigned int*)&h01, *(unsigned int*)&h23);
            ((uint2*)outh)[gn * 32 + fq] = u;
        }
    }
}

// ---------------- 128-wide agg (layer 2): half in, fp32 out ----------------

__global__ void agg128h_kernel(const __half* __restrict__ hsh, const int* __restrict__ offs,
                               const int* __restrict__ csr_src, const float* __restrict__ dinv,
                               const float* __restrict__ bias, float* __restrict__ out, int n) {
    int node = (int)(((long)blockIdx.x * blockDim.x + threadIdx.x) >> 6);
    int lane = threadIdx.x & 63;
    if (node >= n) return;
    int grp = lane >> 5, q = lane & 31;
    int beg = offs[node], end = offs[node + 1];
    float4 acc = make_float4(0.f, 0.f, 0.f, 0.f);
    int eb = beg;
    for (; eb + 16 <= end; eb += 16) {
        int s[8]; uint2 u[8];
#pragma unroll
        for (int j = 0; j < 8; ++j) s[j] = csr_src[eb + grp + 2 * j];
#pragma unroll
        for (int j = 0; j < 8; ++j) u[j] = ((const uint2*)hsh)[(long)s[j] * 32 + q];
#pragma unroll
        for (int j = 0; j < 8; ++j) {
            float2 lo = __half22float2(*(__half2*)&u[j].x);
            float2 hi = __half22float2(*(__half2*)&u[j].y);
            acc.x += lo.x; acc.y += lo.y; acc.z += hi.x; acc.w += hi.y;
        }
    }
    if (eb + 8 <= end) {
        int s[4]; uint2 u[4];
#pragma unroll
        for (int j = 0; j < 4; ++j) s[j] = csr_src[eb + grp + 2 * j];
#pragma unroll
        for (int j = 0; j < 4; ++j) u[j] = ((const uint2*)hsh)[(long)s[j] * 32 + q];
#pragma unroll
        for (int j = 0; j < 4; ++j) {
            float2 lo = __half22float2(*(__half2*)&u[j].x);
            float2 hi = __half22float2(*(__half2*)&u[j].y);
            acc.x += lo.x; acc.y += lo.y; acc.z += hi.x; acc.w += hi.y;
        }
        eb += 8;
    }
    for (int e = eb + grp; e < end; e += 2) {
        uint2 u = ((const uint2*)hsh)[(long)csr_src[e] * 32 + q];
        float2 lo = __half22float2(*(__half2*)&u.x);
        float2 hi = __half22float2(*(__half2*)&u.y);
        acc.x += lo.x; acc.y += lo.y; acc.z += hi.x; acc.w += hi.y;
    }
    acc.x += __shfl_down(acc.x, 32);
    acc.y += __shfl_down(acc.y, 32);
    acc.z += __shfl_down(acc.z, 32);
    acc.w += __shfl_down(acc.w, 32);
    if (grp == 0) {
        float di = dinv[node];
        float4 b = ((const float4*)bias)[q];
        acc.x = fmaxf(acc.x * di + b.x, 0.f);
        acc.y = fmaxf(acc.y * di + b.y, 0.f);
        acc.z = fmaxf(acc.z * di + b.z, 0.f);
        acc.w = fmaxf(acc.w * di + b.w, 0.f);
        ((float4*)(out + (long)node * HIDDEN))[q] = acc;
    }
}

// ---------------- folded layer 3 + pool + head ----------------

// W3l = W3@Wl [128,19], b3l = b3@Wl [19]; multi-block, Wl staged in LDS
__global__ void w3l_kernel(const float* __restrict__ W3, const float* __restrict__ Wl,
                           const float* __restrict__ b3, float* __restrict__ W3l,
                           float* __restrict__ b3l) {
    __shared__ float Wls[HIDDEN * NCLS];
    int tid = threadIdx.x;
    for (int i = tid; i < HIDDEN * NCLS; i += 256) Wls[i] = Wl[i];
    __syncthreads();
    if (blockIdx.x < 10) {
        int o = blockIdx.x * 256 + tid;
        if (o < HIDDEN * NCLS) {
            int i = o / NCLS, j = o % NCLS;
            float acc = 0.f;
#pragma unroll 8
            for (int k = 0; k < HIDDEN; ++k) acc += W3[i * HIDDEN + k] * Wls[k * NCLS + j];
            W3l[o] = acc;
        }
    } else if (tid < NCLS) {
        float acc = 0.f;
#pragma unroll 8
        for (int k = 0; k < HIDDEN; ++k) acc += b3[k] * Wls[k * NCLS + tid];
        b3l[tid] = acc;
    }
}

// y32h[n,32] halves = (h2 @ W3l)*dinv, cols 19..31 zero; 12 nodes/block
__global__ void gemm_y32h_kernel(const float* __restrict__ h2, const float* __restrict__ W3l,
                                 const float* __restrict__ dinv, __half* __restrict__ ys, int n) {
    __shared__ float hs[12][HIDDEN];
    __shared__ float Ws[HIDDEN][20];
    int tid = threadIdx.x;
    long base = (long)blockIdx.x * 12;
    for (int i = tid; i < HIDDEN * NCLS; i += 256) Ws[i / NCLS][i % NCLS] = W3l[i];
    for (int idx = tid; idx < 12 * 32; idx += 256) {
        int node = idx >> 5, q = idx & 31;
        long gn = base + node;
        float4 a = (gn < n) ? ((const float4*)(h2 + gn * HIDDEN))[q]
                            : make_float4(0.f, 0.f, 0.f, 0.f);
        *(float4*)&hs[node][q * 4] = a;
    }
    __syncthreads();
    if (tid < 12 * NCLS) {
        int node = tid / NCLS, j = tid % NCLS;
        long gn = base + node;
        if (gn < n) {
            float acc = 0.f;
#pragma unroll 8
            for (int k = 0; k < HIDDEN; ++k) acc += hs[node][k] * Ws[k][j];
            ys[gn * 32 + j] = __float2half(acc * dinv[gn]);
        }
    }
    for (int idx = tid; idx < 12 * 13; idx += 256) {
        int node = idx / 13, j = 19 + idx % 13;
        long gn = base + node;
        if (gn < n) ys[gn * 32 + j] = __half(0.f);
    }
}

// pool[g] += dinv[d] * sum_e ys[src_e]; wave/node, 4 grp x 16 lanes x half2
__global__ void agg24h_pool_kernel(const __half* __restrict__ ys, const int* __restrict__ offs,
                                   const int* __restrict__ csr_src, const float* __restrict__ dinv,
                                   const int* __restrict__ batch, float* __restrict__ pool, int n) {
    int node = (int)(((long)blockIdx.x * blockDim.x + threadIdx.x) >> 6);
    int lane = threadIdx.x & 63;
    if (node >= n) return;
    int grp = lane >> 4, f = lane & 15;     // lane f covers cols 2f, 2f+1
    int beg = offs[node], end = offs[node + 1];
    float2 acc = {0.f, 0.f};
    int eb = beg;
    for (; eb + 32 <= end; eb += 32) {
        int s[8]; unsigned int u[8];
#pragma unroll
        for (int j = 0; j < 8; ++j) s[j] = csr_src[eb + grp + 4 * j];
#pragma unroll
        for (int j = 0; j < 8; ++j) u[j] = ((const unsigned int*)ys)[(long)s[j] * 16 + f];
#pragma unroll
        for (int j = 0; j < 8; ++j) {
            float2 v = __half22float2(*(__half2*)&u[j]);
            acc.x += v.x; acc.y += v.y;
        }
    }
    if (eb + 16 <= end) {
        int s[4]; unsigned int u[4];
#pragma unroll
        for (int j = 0; j < 4; ++j) s[j] = csr_src[eb + grp + 4 * j];
#pragma unroll
        for (int j = 0; j < 4; ++j) u[j] = ((const unsigned int*)ys)[(long)s[j] * 16 + f];
#pragma unroll
        for (int j = 0; j < 4; ++j) {
            float2 v = __half22float2(*(__half2*)&u[j]);
            acc.x += v.x; acc.y += v.y;
        }
        eb += 16;
    }
    for (int e = eb + grp; e < end; e += 4) {
        unsigned int u = ((const unsigned int*)ys)[(long)csr_src[e] * 16 + f];
        float2 v = __half22float2(*(__half2*)&u);
        acc.x += v.x; acc.y += v.y;
    }
    acc.x += __shfl_down(acc.x, 32);
    acc.y += __shfl_down(acc.y, 32);
    acc.x += __shfl_down(acc.x, 16);
    acc.y += __shfl_down(acc.y, 16);
    if (lane < 16) {
        int g = batch[node];
        float sc = dinv[node];
        int c0 = 2 * f;
        if (c0 < NCLS) atomicAdd(&pool[(long)g * 24 + c0], acc.x * sc);
        if (c0 + 1 < NCLS) atomicAdd(&pool[(long)g * 24 + c0 + 1], acc.y * sc);
    }
}

__global__ void final_kernel(const float* __restrict__ pool, const float* __restrict__ cnt,
                             const float* __restrict__ b3l, const float* __restrict__ bl,
                             float* __restrict__ out, int G) {
    int i = blockIdx.x * blockDim.x + threadIdx.x;
    if (i >= G * NCLS) return;
    int g = i / NCLS, j = i % NCLS;
    float c = cnt[g];
    out[i] = (c > 0.f) ? pool[(long)g * 24 + j] / c + b3l[j] + bl[j] : bl[j];
}

// ---------------- launch ----------------

static inline size_t align256(size_t x) { return (x + 255) & ~(size_t)255; }

extern "C" void kernel_launch(void* const* d_in, const int* in_sizes, int n_in,
                              void* d_out, int out_size, void* d_ws, size_t ws_size,
                              hipStream_t stream) {
    const float* x    = (const float*)d_in[0];
    const int*   ei   = (const int*)d_in[1];
    const int*   batch= (const int*)d_in[2];
    const float* W1   = (const float*)d_in[3];
    const float* b1   = (const float*)d_in[4];
    const float* W2   = (const float*)d_in[5];
    const float* b2   = (const float*)d_in[6];
    const float* W3   = (const float*)d_in[7];
    const float* b3   = (const float*)d_in[8];
    const float* Wl   = (const float*)d_in[9];
    const float* bl   = (const float*)d_in[10];
    float* out = (float*)d_out;

    const int N = in_sizes[0] / F_IN;
    const int E = in_sizes[1] / 2;
    const int G = out_size / NCLS;
    const int* src = ei;
    const int* dst = ei + E;
    const int nblk = (N + 1023) / 1024;

    // workspace carve-up
    char* p = (char*)d_ws;
    size_t off = 0;
    int*    deg_cnt = (int*)(p + off);   off = align256(off + (size_t)N * 4);
    int*    offs    = (int*)(p + off);   off = align256(off + (size_t)(N + 1) * 4);
    int*    cursor  = (int*)(p + off);   off = align256(off + (size_t)N * 4);
    int*    linc    = (int*)(p + off);   off = align256(off + (size_t)N * 4);
    int*    btot    = (int*)(p + off);   off = align256(off + 1024 * 4);
    int*    boff    = (int*)(p + off);   off = align256(off + 1024 * 4);
    float*  dinv    = (float*)(p + off); off = align256(off + (size_t)N * 4);
    int*    csr_src = (int*)(p + off);   off = align256(off + (size_t)(E + N) * 4);
    float*  x16     = (float*)(p + off); off = align256(off + (size_t)N * 16 * 4);
    float*  z16     = (float*)(p + off); off = align256(off + (size_t)N * 16 * 4);
    __half* hsh     = (__half*)(p + off);off = align256(off + (size_t)N * HIDDEN * 2);
    __half* y32h    = (__half*)(p + off);off = align256(off + (size_t)N * 32 * 2);
    float*  W3l     = (float*)(p + off); off = align256(off + (size_t)HIDDEN * NCLS * 4);
    float*  b3l     = (float*)(p + off); off = align256(off + (size_t)NCLS * 4);
    float*  pool    = (float*)(p + off); off = align256(off + (size_t)G * 25 * 4);
    float*  gcnt    = pool + (size_t)G * 24;
    float*  h_a     = (float*)(p + off); off = align256(off + (size_t)N * HIDDEN * 4);
    (void)ws_size; (void)n_in;

    hipMemsetAsync(deg_cnt, 0, (size_t)N * 4, stream);
    hipMemsetAsync(pool, 0, (size_t)G * 25 * 4, stream);

    // CSR build (self-loop in slot 0 of each segment)
    count_kernel<<<(E + 255) / 256, 256, 0, stream>>>(dst, deg_cnt, E);
    scanA_kernel<<<nblk, 1024, 0, stream>>>(deg_cnt, linc, btot, N);
    scanB_kernel<<<1, 1024, 0, stream>>>(btot, boff, offs, N, nblk);
    scanC_kernel<<<(N + 255) / 256, 256, 0, stream>>>(deg_cnt, linc, boff, offs, cursor,
                                                      csr_src, dinv, batch, gcnt, x, x16, N);
    fill_csr_kernel<<<(E + 255) / 256, 256, 0, stream>>>(src, dst, cursor, csr_src, E);
    w3l_kernel<<<11, 256, 0, stream>>>(W3, Wl, b3, W3l, b3l);

    const int aggBlocks = (N + 3) / 4;  // 4 waves/block, wave per node

    // layer 1: z16 = dinv * sum(x16) ; h1 = relu(z16@W1+b1) -> h_a
    agg16_kernel<<<aggBlocks, 256, 0, stream>>>(x16, offs, csr_src, dinv, z16, N);
    gemm_in_kernel<<<(N + 7) / 8, 256, 0, stream>>>(z16, W1, b1, h_a, N);

    // layer 2: hsh = half((h1@W2)*dinv) ; h2 = relu(dinv*sum hsh + b2) -> h_a
    gemm128h_kernel<<<(N + GM_NODES - 1) / GM_NODES, 256, 0, stream>>>(h_a, W2, dinv, hsh, N);
    agg128h_kernel<<<aggBlocks, 256, 0, stream>>>(hsh, offs, csr_src, dinv, b2, h_a, N);

    // folded layer 3 + pool
    gemm_y32h_kernel<<<(N + 11) / 12, 256, 0, stream>>>(h_a, W3l, dinv, y32h, N);
    agg24h_pool_kernel<<<aggBlocks, 256, 0, stream>>>(y32h, offs, csr_src, dinv, batch, pool, N);
    final_kernel<<<(G * NCLS + 255) / 256, 256, 0, stream>>>(pool, gcnt, b3l, bl, out, G);
}

// Round 7
// 283.872 us; speedup vs baseline: 2.7956x; 1.2127x over previous
//
#include <hip/hip_runtime.h>
#include <hip/hip_bf16.h>
#include <hip/hip_fp16.h>

// GCN2: 3x GCNConv(relu,relu,none) + global_mean_pool + linear head.
// R7: CSR build rewritten sort-free-bucketed. Old fill_csr did random 4B
// scatters -> 52 MB of partial-line HBM writebacks (48us) + count's random
// atomics (~30us). New: hist(dst>>9) -> bucket scan -> LDS-staged scatter of
// packed (src|dst<<16) edges (dense ~256B bursts) -> per-bucket build with
// all random writes in LDS, dense csr16/offs/dinv/x16 output. csr = ushort.

#define HIDDEN 128
#define F_IN 11
#define NCLS 19
#define NBITS 9
#define NB 128
#define RNODES 512
#define EPB 8192

// ---------------- bucketed CSR build ----------------

__global__ void hist_kernel(const int* __restrict__ dst, int* __restrict__ bhist, int E) {
    __shared__ int h[NB];
    int tid = threadIdx.x;
    for (int i = tid; i < NB; i += 256) h[i] = 0;
    __syncthreads();
    int lim = min((blockIdx.x + 1) * EPB, E);
    for (int e = blockIdx.x * EPB + tid; e < lim; e += 256)
        atomicAdd(&h[dst[e] >> NBITS], 1);
    __syncthreads();
    for (int i = tid; i < NB; i += 256) if (h[i]) atomicAdd(&bhist[i], h[i]);
}

// 128 threads: exclusive scan of bhist -> bstart/bcur; bstart[128]; offs[N]=E+N
__global__ void bucket_scan_kernel(const int* __restrict__ bhist, int* __restrict__ bstart,
                                   int* __restrict__ bcur, int* __restrict__ offs,
                                   int n, int E) {
    __shared__ int cw[2];
    int tid = threadIdx.x, lane = tid & 63, w = tid >> 6;
    int v = bhist[tid], xv = v;
#pragma unroll
    for (int d = 1; d < 64; d <<= 1) {
        int t = __shfl_up(xv, d, 64);
        if (lane >= d) xv += t;
    }
    if (lane == 63) cw[w] = xv;
    __syncthreads();
    int excl = xv - v + ((w == 1) ? cw[0] : 0);
    bstart[tid] = excl;
    bcur[tid] = excl;
    if (tid == 127) bstart[128] = excl + v;
    if (tid == 0) offs[n] = E + n;
}

// per block: 8192 edges -> LDS bucket-sorted -> dense run copy-out
__global__ void scatter_kernel(const int* __restrict__ src, const int* __restrict__ dst,
                               int* __restrict__ bcur, unsigned int* __restrict__ bents, int E) {
    __shared__ int hist[NB];
    __shared__ int binoff[NB];
    __shared__ int runbase[NB];
    __shared__ unsigned int ebuf[EPB];
    __shared__ unsigned short binOf[EPB];
    __shared__ int cw[2];
    int tid = threadIdx.x, lane = tid & 63, w = tid >> 6;
    int base = blockIdx.x * EPB;
    int cnt = min(EPB, E - base);
    for (int i = tid; i < NB; i += 256) hist[i] = 0;
    __syncthreads();
    unsigned int pk[32];
    int rk[32];
#pragma unroll
    for (int j = 0; j < 32; ++j) {
        int idx = tid + 256 * j;
        if (idx < cnt) {
            int e = base + idx;
            int s = src[e], d = dst[e];
            pk[j] = (unsigned int)s | ((unsigned int)d << 16);
            int bin = d >> NBITS;
            int r = atomicAdd(&hist[bin], 1);
            rk[j] = r | (bin << 16);
        } else rk[j] = -1;
    }
    __syncthreads();
    int v = 0, xv = 0;
    if (tid < NB) {
        v = hist[tid]; xv = v;
#pragma unroll
        for (int d = 1; d < 64; d <<= 1) {
            int t = __shfl_up(xv, d, 64);
            if (lane >= d) xv += t;
        }
        if (lane == 63) cw[w] = xv;
    }
    __syncthreads();
    if (tid < NB) {
        binoff[tid] = xv - v + ((w == 1) ? cw[0] : 0);
        runbase[tid] = v ? atomicAdd(&bcur[tid], v) : 0;
    }
    __syncthreads();
#pragma unroll
    for (int j = 0; j < 32; ++j) {
        if (rk[j] >= 0) {
            int bin = rk[j] >> 16, r = rk[j] & 0xFFFF;
            int pos = binoff[bin] + r;
            ebuf[pos] = pk[j];
            binOf[pos] = (unsigned short)bin;
        }
    }
    __syncthreads();
    for (int i = tid; i < cnt; i += 256) {
        int bin = binOf[i];
        bents[runbase[bin] + (i - binoff[bin])] = ebuf[i];
    }
}

// per bucket: counts -> scan -> LDS scatter (self + srcs) -> dense writes.
// also emits offs, dinv, gcnt, x16 for this node range.
__global__ void build_kernel(const unsigned int* __restrict__ bents, const int* __restrict__ bstart,
                             const float* __restrict__ x, const int* __restrict__ batch,
                             int* __restrict__ offs, unsigned short* __restrict__ csr16,
                             float* __restrict__ dinv, float* __restrict__ gcnt,
                             float* __restrict__ x16, int n) {
    __shared__ int counts[RNODES];
    __shared__ int lp[RNODES];
    __shared__ int lcur[RNODES];
    __shared__ unsigned short outl[13824];
    __shared__ int wsums[8];
    int tid = threadIdx.x;          // 1024
    int lane = tid & 63, w = tid >> 6;
    int b = blockIdx.x;
    int base = b << NBITS;
    int nn = min(RNODES, n - base);
    int ebase = bstart[b], ecnt = bstart[b + 1] - ebase;
    for (int i = tid; i < RNODES; i += 1024) counts[i] = 0;
    __syncthreads();
    for (int e = tid; e < ecnt; e += 1024)
        atomicAdd(&counts[(bents[ebase + e] >> 16) - base], 1);
    __syncthreads();
    // scan of (counts[i]+1) over 512 entries: waves 0..7
    int v = 0, xv = 0;
    if (tid < RNODES) {
        v = (tid < nn) ? counts[tid] + 1 : 0;
        xv = v;
#pragma unroll
        for (int d = 1; d < 64; d <<= 1) {
            int t = __shfl_up(xv, d, 64);
            if (lane >= d) xv += t;
        }
        if (lane == 63) wsums[w] = xv;
    }
    __syncthreads();
    if (tid < 64) {
        int s = (lane < 8) ? wsums[lane] : 0;
#pragma unroll
        for (int d = 1; d < 8; d <<= 1) {
            int t = __shfl_up(s, d, 64);
            if (lane >= d) s += t;
        }
        if (lane < 8) wsums[lane] = s;
    }
    __syncthreads();
    if (tid < nn) {
        int excl = xv - v + ((w > 0) ? wsums[w - 1] : 0);
        lp[tid] = excl;
        lcur[tid] = excl + 1;
        outl[excl] = (unsigned short)(base + tid);        // self-loop slot 0
        offs[base + tid] = ebase + base + excl;
        atomicAdd(&gcnt[batch[base + tid]], 1.0f);
    }
    __syncthreads();
    for (int e = tid; e < ecnt; e += 1024) {
        unsigned int pk = bents[ebase + e];
        int i = (int)(pk >> 16) - base;
        int r = atomicAdd(&lcur[i], 1);
        outl[r] = (unsigned short)(pk & 0xFFFFu);
    }
    __syncthreads();
    int total = ecnt + nn;
    for (int i = tid; i < total; i += 1024)
        csr16[ebase + base + i] = outl[i];
    for (int idx = tid; idx < nn * 16; idx += 1024) {
        int i = idx >> 4, j = idx & 15;
        float di = 1.0f / sqrtf((float)(counts[i] + 1));
        if (j == 0) dinv[base + i] = di;
        x16[(long)(base + i) * 16 + j] = (j < F_IN) ? x[(long)(base + i) * F_IN + j] * di : 0.f;
    }
}

// ---------------- layer 1 ----------------

__global__ void agg16_kernel(const float* __restrict__ xs, const int* __restrict__ offs,
                             const unsigned short* __restrict__ csr16, const float* __restrict__ dinv,
                             float* __restrict__ z16, int n) {
    int node = (int)(((long)blockIdx.x * blockDim.x + threadIdx.x) >> 6);
    int lane = threadIdx.x & 63;
    if (node >= n) return;
    int grp = lane >> 4, f = lane & 15;
    int beg = offs[node], end = offs[node + 1];
    float acc = 0.f;
    int eb = beg;
    for (; eb + 16 <= end; eb += 16) {
        int s[4]; float v[4];
#pragma unroll
        for (int j = 0; j < 4; ++j) s[j] = csr16[eb + grp + 4 * j];
#pragma unroll
        for (int j = 0; j < 4; ++j) v[j] = xs[(long)s[j] * 16 + f];
#pragma unroll
        for (int j = 0; j < 4; ++j) acc += v[j];
    }
    if (eb + 8 <= end) {
        int s0 = csr16[eb + grp], s1 = csr16[eb + grp + 4];
        acc += xs[(long)s0 * 16 + f] + xs[(long)s1 * 16 + f];
        eb += 8;
    }
    for (int e = eb + grp; e < end; e += 4)
        acc += xs[(long)csr16[e] * 16 + f];
    acc += __shfl_down(acc, 32);
    acc += __shfl_down(acc, 16);
    if (lane < 16) z16[(long)node * 16 + lane] = acc * dinv[node];
}

__global__ void gemm_in_kernel(const float* __restrict__ z16, const float* __restrict__ W1,
                               const float* __restrict__ b1, float* __restrict__ out, int n) {
    __shared__ float Ws[F_IN * HIDDEN];
    __shared__ float bs[HIDDEN];
    __shared__ float zs[8][16];
    int tid = threadIdx.x;
    long base = (long)blockIdx.x * 8;
    for (int i = tid; i < F_IN * HIDDEN; i += 256) Ws[i] = W1[i];
    if (tid < HIDDEN) bs[tid] = b1[tid];
    if (tid < 128) {
        int ln = tid >> 4, f = tid & 15;
        long gn = base + ln;
        zs[ln][f] = (gn < n) ? z16[gn * 16 + f] : 0.f;
    }
    __syncthreads();
    int f = tid & 127, half = tid >> 7;
#pragma unroll
    for (int r = 0; r < 4; ++r) {
        int ln = half * 4 + r;
        long gn = base + ln;
        float acc = bs[f];
#pragma unroll
        for (int k = 0; k < F_IN; ++k) acc += zs[ln][k] * Ws[k * HIDDEN + f];
        if (gn < n) out[gn * HIDDEN + f] = fmaxf(acc, 0.f);
    }
}

// ---------------- 128x128 GEMM (layer 2), half output scaled by dinv ----------------

#define GM_NODES 64
__global__ void gemm128h_kernel(const float* __restrict__ A, const float* __restrict__ W,
                                const float* __restrict__ dinv, __half* __restrict__ outh,
                                int n) {
    __shared__ float Ws[32][HIDDEN];
    __shared__ float As[GM_NODES][36];
    int tid = threadIdx.x;
    long base = (long)blockIdx.x * GM_NODES;
    int fq = tid & 31;
    int nb = (tid >> 5) * 8;

    float4 acc[8];
#pragma unroll
    for (int i = 0; i < 8; ++i) acc[i] = make_float4(0.f, 0.f, 0.f, 0.f);

    for (int c = 0; c < 4; ++c) {
        __syncthreads();
#pragma unroll
        for (int r = 0; r < 4; ++r) {
            int idx = tid + 256 * r;
            int k = idx >> 5, f4 = idx & 31;
            ((float4*)Ws[k])[f4] = ((const float4*)(W + (c * 32 + k) * HIDDEN))[f4];
        }
#pragma unroll
        for (int r = 0; r < 2; ++r) {
            int idx = tid + 256 * r;
            int node = idx >> 3, kq = idx & 7;
            long gn = base + node;
            float4 a = (gn < n) ? ((const float4*)(A + gn * HIDDEN + c * 32))[kq]
                                : make_float4(0.f, 0.f, 0.f, 0.f);
            *(float4*)&As[node][kq * 4] = a;
        }
        __syncthreads();
#pragma unroll
        for (int k = 0; k < 32; ++k) {
            float4 w = ((float4*)Ws[k])[fq];
            float a0 = As[nb + 0][k], a1 = As[nb + 1][k];
            float a2 = As[nb + 2][k], a3 = As[nb + 3][k];
            float a4 = As[nb + 4][k], a5 = As[nb + 5][k];
            float a6 = As[nb + 6][k], a7 = As[nb + 7][k];
            acc[0].x += a0 * w.x; acc[0].y += a0 * w.y; acc[0].z += a0 * w.z; acc[0].w += a0 * w.w;
            acc[1].x += a1 * w.x; acc[1].y += a1 * w.y; acc[1].z += a1 * w.z; acc[1].w += a1 * w.w;
            acc[2].x += a2 * w.x; acc[2].y += a2 * w.y; acc[2].z += a2 * w.z; acc[2].w += a2 * w.w;
            acc[3].x += a3 * w.x; acc[3].y += a3 * w.y; acc[3].z += a3 * w.z; acc[3].w += a3 * w.w;
            acc[4].x += a4 * w.x; acc[4].y += a4 * w.y; acc[4].z += a4 * w.z; acc[4].w += a4 * w.w;
            acc[5].x += a5 * w.x; acc[5].y += a5 * w.y; acc[5].z += a5 * w.z; acc[5].w += a5 * w.w;
            acc[6].x += a6 * w.x; acc[6].y += a6 * w.y; acc[6].z += a6 * w.z; acc[6].w += a6 * w.w;
            acc[7].x += a7 * w.x; acc[7].y += a7 * w.y; acc[7].z += a7 * w.z; acc[7].w += a7 * w.w;
        }
    }
#pragma unroll
    for (int i = 0; i < 8; ++i) {
        long gn = base + nb + i;
        if (gn < n) {
            float di = dinv[gn];
            __half2 h01 = __floats2half2_rn(acc[i].x * di, acc[i].y * di);
            __half2 h23 = __floats2half2_rn(acc[i].z * di, acc[i].w * di);
            uint2 u = make_uint2(*(unsigned int*)&h01, *(unsigned int*)&h23);
            ((uint2*)outh)[gn * 32 + fq] = u;
        }
    }
}

// ---------------- 128-wide agg (layer 2): half in, fp32 out ----------------

__global__ void agg128h_kernel(const __half* __restrict__ hsh, const int* __restrict__ offs,
                               const unsigned short* __restrict__ csr16, const float* __restrict__ dinv,
                               const float* __restrict__ bias, float* __restrict__ out, int n) {
    int node = (int)(((long)blockIdx.x * blockDim.x + threadIdx.x) >> 6);
    int lane = threadIdx.x & 63;
    if (node >= n) return;
    int grp = lane >> 5, q = lane & 31;
    int beg = offs[node], end = offs[node + 1];
    float4 acc = make_float4(0.f, 0.f, 0.f, 0.f);
    int eb = beg;
    for (; eb + 16 <= end; eb += 16) {
        int s[8]; uint2 u[8];
#pragma unroll
        for (int j = 0; j < 8; ++j) s[j] = csr16[eb + grp + 2 * j];
#pragma unroll
        for (int j = 0; j < 8; ++j) u[j] = ((const uint2*)hsh)[(long)s[j] * 32 + q];
#pragma unroll
        for (int j = 0; j < 8; ++j) {
            float2 lo = __half22float2(*(__half2*)&u[j].x);
            float2 hi = __half22float2(*(__half2*)&u[j].y);
            acc.x += lo.x; acc.y += lo.y; acc.z += hi.x; acc.w += hi.y;
        }
    }
    if (eb + 8 <= end) {
        int s[4]; uint2 u[4];
#pragma unroll
        for (int j = 0; j < 4; ++j) s[j] = csr16[eb + grp + 2 * j];
#pragma unroll
        for (int j = 0; j < 4; ++j) u[j] = ((const uint2*)hsh)[(long)s[j] * 32 + q];
#pragma unroll
        for (int j = 0; j < 4; ++j) {
            float2 lo = __half22float2(*(__half2*)&u[j].x);
            float2 hi = __half22float2(*(__half2*)&u[j].y);
            acc.x += lo.x; acc.y += lo.y; acc.z += hi.x; acc.w += hi.y;
        }
        eb += 8;
    }
    for (int e = eb + grp; e < end; e += 2) {
        uint2 u = ((const uint2*)hsh)[(long)csr16[e] * 32 + q];
        float2 lo = __half22float2(*(__half2*)&u.x);
        float2 hi = __half22float2(*(__half2*)&u.y);
        acc.x += lo.x; acc.y += lo.y; acc.z += hi.x; acc.w += hi.y;
    }
    acc.x += __shfl_down(acc.x, 32);
    acc.y += __shfl_down(acc.y, 32);
    acc.z += __shfl_down(acc.z, 32);
    acc.w += __shfl_down(acc.w, 32);
    if (grp == 0) {
        float di = dinv[node];
        float4 b = ((const float4*)bias)[q];
        acc.x = fmaxf(acc.x * di + b.x, 0.f);
        acc.y = fmaxf(acc.y * di + b.y, 0.f);
        acc.z = fmaxf(acc.z * di + b.z, 0.f);
        acc.w = fmaxf(acc.w * di + b.w, 0.f);
        ((float4*)(out + (long)node * HIDDEN))[q] = acc;
    }
}

// ---------------- folded layer 3 + pool + head ----------------

__global__ void w3l_kernel(const float* __restrict__ W3, const float* __restrict__ Wl,
                           const float* __restrict__ b3, float* __restrict__ W3l,
                           float* __restrict__ b3l) {
    __shared__ float Wls[HIDDEN * NCLS];
    int tid = threadIdx.x;
    for (int i = tid; i < HIDDEN * NCLS; i += 256) Wls[i] = Wl[i];
    __syncthreads();
    if (blockIdx.x < 10) {
        int o = blockIdx.x * 256 + tid;
        if (o < HIDDEN * NCLS) {
            int i = o / NCLS, j = o % NCLS;
            float acc = 0.f;
#pragma unroll 8
            for (int k = 0; k < HIDDEN; ++k) acc += W3[i * HIDDEN + k] * Wls[k * NCLS + j];
            W3l[o] = acc;
        }
    } else if (tid < NCLS) {
        float acc = 0.f;
#pragma unroll 8
        for (int k = 0; k < HIDDEN; ++k) acc += b3[k] * Wls[k * NCLS + tid];
        b3l[tid] = acc;
    }
}

__global__ void gemm_y32h_kernel(const float* __restrict__ h2, const float* __restrict__ W3l,
                                 const float* __restrict__ dinv, __half* __restrict__ ys, int n) {
    __shared__ float hs[12][HIDDEN];
    __shared__ float Ws[HIDDEN][20];
    int tid = threadIdx.x;
    long base = (long)blockIdx.x * 12;
    for (int i = tid; i < HIDDEN * NCLS; i += 256) Ws[i / NCLS][i % NCLS] = W3l[i];
    for (int idx = tid; idx < 12 * 32; idx += 256) {
        int node = idx >> 5, q = idx & 31;
        long gn = base + node;
        float4 a = (gn < n) ? ((const float4*)(h2 + gn * HIDDEN))[q]
                            : make_float4(0.f, 0.f, 0.f, 0.f);
        *(float4*)&hs[node][q * 4] = a;
    }
    __syncthreads();
    if (tid < 12 * NCLS) {
        int node = tid / NCLS, j = tid % NCLS;
        long gn = base + node;
        if (gn < n) {
            float acc = 0.f;
#pragma unroll 8
            for (int k = 0; k < HIDDEN; ++k) acc += hs[node][k] * Ws[k][j];
            ys[gn * 32 + j] = __float2half(acc * dinv[gn]);
        }
    }
    for (int idx = tid; idx < 12 * 13; idx += 256) {
        int node = idx / 13, j = 19 + idx % 13;
        long gn = base + node;
        if (gn < n) ys[gn * 32 + j] = __half(0.f);
    }
}

__global__ void agg24h_pool_kernel(const __half* __restrict__ ys, const int* __restrict__ offs,
                                   const unsigned short* __restrict__ csr16, const float* __restrict__ dinv,
                                   const int* __restrict__ batch, float* __restrict__ pool, int n) {
    int node = (int)(((long)blockIdx.x * blockDim.x + threadIdx.x) >> 6);
    int lane = threadIdx.x & 63;
    if (node >= n) return;
    int grp = lane >> 4, f = lane & 15;
    int beg = offs[node], end = offs[node + 1];
    float2 acc = {0.f, 0.f};
    int eb = beg;
    for (; eb + 32 <= end; eb += 32) {
        int s[8]; unsigned int u[8];
#pragma unroll
        for (int j = 0; j < 8; ++j) s[j] = csr16[eb + grp + 4 * j];
#pragma unroll
        for (int j = 0; j < 8; ++j) u[j] = ((const unsigned int*)ys)[(long)s[j] * 16 + f];
#pragma unroll
        for (int j = 0; j < 8; ++j) {
            float2 v = __half22float2(*(__half2*)&u[j]);
            acc.x += v.x; acc.y += v.y;
        }
    }
    if (eb + 16 <= end) {
        int s[4]; unsigned int u[4];
#pragma unroll
        for (int j = 0; j < 4; ++j) s[j] = csr16[eb + grp + 4 * j];
#pragma unroll
        for (int j = 0; j < 4; ++j) u[j] = ((const unsigned int*)ys)[(long)s[j] * 16 + f];
#pragma unroll
        for (int j = 0; j < 4; ++j) {
            float2 v = __half22float2(*(__half2*)&u[j]);
            acc.x += v.x; acc.y += v.y;
        }
        eb += 16;
    }
    for (int e = eb + grp; e < end; e += 4) {
        unsigned int u = ((const unsigned int*)ys)[(long)csr16[e] * 16 + f];
        float2 v = __half22float2(*(__half2*)&u);
        acc.x += v.x; acc.y += v.y;
    }
    acc.x += __shfl_down(acc.x, 32);
    acc.y += __shfl_down(acc.y, 32);
    acc.x += __shfl_down(acc.x, 16);
    acc.y += __shfl_down(acc.y, 16);
    if (lane < 16) {
        int g = batch[node];
        float sc = dinv[node];
        int c0 = 2 * f;
        if (c0 < NCLS) atomicAdd(&pool[(long)g * 24 + c0], acc.x * sc);
        if (c0 + 1 < NCLS) atomicAdd(&pool[(long)g * 24 + c0 + 1], acc.y * sc);
    }
}

__global__ void final_kernel(const float* __restrict__ pool, const float* __restrict__ cnt,
                             const float* __restrict__ b3l, const float* __restrict__ bl,
                             float* __restrict__ out, int G) {
    int i = blockIdx.x * blockDim.x + threadIdx.x;
    if (i >= G * NCLS) return;
    int g = i / NCLS, j = i % NCLS;
    float c = cnt[g];
    out[i] = (c > 0.f) ? pool[(long)g * 24 + j] / c + b3l[j] + bl[j] : bl[j];
}

// ---------------- launch ----------------

static inline size_t align256(size_t x) { return (x + 255) & ~(size_t)255; }

extern "C" void kernel_launch(void* const* d_in, const int* in_sizes, int n_in,
                              void* d_out, int out_size, void* d_ws, size_t ws_size,
                              hipStream_t stream) {
    const float* x    = (const float*)d_in[0];
    const int*   ei   = (const int*)d_in[1];
    const int*   batch= (const int*)d_in[2];
    const float* W1   = (const float*)d_in[3];
    const float* b1   = (const float*)d_in[4];
    const float* W2   = (const float*)d_in[5];
    const float* b2   = (const float*)d_in[6];
    const float* W3   = (const float*)d_in[7];
    const float* b3   = (const float*)d_in[8];
    const float* Wl   = (const float*)d_in[9];
    const float* bl   = (const float*)d_in[10];
    float* out = (float*)d_out;

    const int N = in_sizes[0] / F_IN;
    const int E = in_sizes[1] / 2;
    const int G = out_size / NCLS;
    const int* src = ei;
    const int* dst = ei + E;
    const int nSB = (E + EPB - 1) / EPB;           // scatter/hist blocks
    const int nBK = (N + RNODES - 1) / RNODES;     // buckets

    // workspace carve-up
    char* p = (char*)d_ws;
    size_t off = 0;
    int*            bhist  = (int*)(p + off);            off = align256(off + NB * 4);
    int*            bstart = (int*)(p + off);            off = align256(off + (NB + 1) * 4);
    int*            bcur   = (int*)(p + off);            off = align256(off + NB * 4);
    unsigned int*   bents  = (unsigned int*)(p + off);   off = align256(off + (size_t)E * 4);
    unsigned short* csr16  = (unsigned short*)(p + off); off = align256(off + (size_t)(E + N) * 2);
    int*            offs   = (int*)(p + off);            off = align256(off + (size_t)(N + 1) * 4);
    float*          dinv   = (float*)(p + off);          off = align256(off + (size_t)N * 4);
    float*          x16    = (float*)(p + off);          off = align256(off + (size_t)N * 16 * 4);
    float*          z16    = (float*)(p + off);          off = align256(off + (size_t)N * 16 * 4);
    __half*         hsh    = (__half*)(p + off);         off = align256(off + (size_t)N * HIDDEN * 2);
    __half*         y32h   = (__half*)(p + off);         off = align256(off + (size_t)N * 32 * 2);
    float*          W3l    = (float*)(p + off);          off = align256(off + (size_t)HIDDEN * NCLS * 4);
    float*          b3l    = (float*)(p + off);          off = align256(off + (size_t)NCLS * 4);
    float*          pool   = (float*)(p + off);          off = align256(off + (size_t)G * 25 * 4);
    float*          gcnt   = pool + (size_t)G * 24;
    float*          h_a    = (float*)(p + off);          off = align256(off + (size_t)N * HIDDEN * 4);
    (void)ws_size; (void)n_in;

    hipMemsetAsync(bhist, 0, NB * 4, stream);
    hipMemsetAsync(pool, 0, (size_t)G * 25 * 4, stream);

    // bucketed CSR build
    hist_kernel<<<nSB, 256, 0, stream>>>(dst, bhist, E);
    bucket_scan_kernel<<<1, 128, 0, stream>>>(bhist, bstart, bcur, offs, N, E);
    scatter_kernel<<<nSB, 256, 0, stream>>>(src, dst, bcur, bents, E);
    build_kernel<<<nBK, 1024, 0, stream>>>(bents, bstart, x, batch, offs, csr16,
                                           dinv, gcnt, x16, N);
    w3l_kernel<<<11, 256, 0, stream>>>(W3, Wl, b3, W3l, b3l);

    const int aggBlocks = (N + 3) / 4;  // 4 waves/block, wave per node

    // layer 1: z16 = dinv * sum(x16) ; h1 = relu(z16@W1+b1) -> h_a
    agg16_kernel<<<aggBlocks, 256, 0, stream>>>(x16, offs, csr16, dinv, z16, N);
    gemm_in_kernel<<<(N + 7) / 8, 256, 0, stream>>>(z16, W1, b1, h_a, N);

    // layer 2: hsh = half((h1@W2)*dinv) ; h2 = relu(dinv*sum hsh + b2) -> h_a
    gemm128h_kernel<<<(N + GM_NODES - 1) / GM_NODES, 256, 0, stream>>>(h_a, W2, dinv, hsh, N);
    agg128h_kernel<<<aggBlocks, 256, 0, stream>>>(hsh, offs, csr16, dinv, b2, h_a, N);

    // folded layer 3 + pool
    gemm_y32h_kernel<<<(N + 11) / 12, 256, 0, stream>>>(h_a, W3l, dinv, y32h, N);
    agg24h_pool_kernel<<<aggBlocks, 256, 0, stream>>>(y32h, offs, csr16, dinv, batch, pool, N);
    final_kernel<<<(G * NCLS + 255) / 256, 256, 0, stream>>>(pool, gcnt, b3l, bl, out, G);
}